// Round 4
// baseline (2545.636 us; speedup 1.0000x reference)
//
#include <hip/hip_runtime.h>

// GCN_56521769616159 R3 (resubmit; R3 bench was GPUAcquisitionTimeout):
// coarse bucket partition (dst>>8, 391 buckets) with LDS-cursor scatter of
// (src|dstlow, coef) replaces exact CSR fill (which had 16x write
// amplification: 106MB HBM writes for a 6.4MB array). Gather is one block per
// bucket accumulating into a 64KB LDS tile via ds_add_f32, fused
// residual+LN+ReLU epilogue.

static constexpr int NN    = 100000;
static constexpr int NE    = 1600000;
static constexpr int HF    = 64;
static constexpr int NNP   = 100352;        // NN padded to 256
static constexpr int NBUK  = 391;           // ceil(NN/256): bucket = dst>>8
static constexpr int PBLK  = 512;           // partition blocks
static constexpr int CHUNK = NE / PBLK;     // 3125 edges per partition block
static constexpr int SCN   = NBUK * PBLK;   // 200192 = 782*256 exactly
#define EPSV 1e-5f

__global__ __launch_bounds__(256) void k_zero(int* __restrict__ c) {
    int i = blockIdx.x * 256 + threadIdx.x;
    if (i < NN) c[i] = 0;
}

// Per-node in-degree (dst histogram, no self-loop).
__global__ __launch_bounds__(256) void k_hist(const int* __restrict__ ei,
                                              int* __restrict__ cnt) {
    int e = blockIdx.x * 256 + threadIdx.x;
    if (e < NE) atomicAdd(&cnt[ei[NE + e]], 1);
}

__global__ __launch_bounds__(256) void k_dinv(const int* __restrict__ cnt,
                                              float* __restrict__ dinv) {
    int i = blockIdx.x * 256 + threadIdx.x;
    if (i < NN) dinv[i] = rsqrtf((float)cnt[i] + 1.0f);  // +1 self-loop
}

// Per-block bucket histogram: bh[blk][buk] (contiguous per block -> coalesced).
__global__ __launch_bounds__(256) void k_bhist(const int* __restrict__ ei,
                                               int* __restrict__ bh) {
    __shared__ int cnts[NBUK];
    for (int b = threadIdx.x; b < NBUK; b += 256) cnts[b] = 0;
    __syncthreads();
    int base = blockIdx.x * CHUNK;
    for (int k = threadIdx.x; k < CHUNK; k += 256)
        atomicAdd(&cnts[ei[NE + base + k] >> 8], 1);
    __syncthreads();
    for (int b = threadIdx.x; b < NBUK; b += 256)
        bh[blockIdx.x * NBUK + b] = cnts[b];
}

// Exclusive scan of bh in bucket-major order -> offs[buk*PBLK + blk].
// scan1: per-block Hillis-Steele (transposed read); scan2: block sums; scan3: add back.
__global__ __launch_bounds__(256) void k_scan1g(const int* __restrict__ bh,
                                                int* __restrict__ offs,
                                                int* __restrict__ bsum) {
    __shared__ int sm[256];
    int i = blockIdx.x * 256 + threadIdx.x;      // i < SCN always
    int buk = i >> 9, blk = i & (PBLK - 1);
    int x = bh[blk * NBUK + buk];
    sm[threadIdx.x] = x;
    __syncthreads();
    int v = x;
    for (int off = 1; off < 256; off <<= 1) {
        int t = (threadIdx.x >= (unsigned)off) ? sm[threadIdx.x - off] : 0;
        __syncthreads();
        v += t;
        sm[threadIdx.x] = v;
        __syncthreads();
    }
    offs[i] = v - x;
    if (threadIdx.x == 255) bsum[blockIdx.x] = v;
}

__global__ __launch_bounds__(1024) void k_scan2g(int* __restrict__ bsum, int nb) {
    __shared__ int sm[1024];
    int t = threadIdx.x;
    int x = (t < nb) ? bsum[t] : 0;
    sm[t] = x;
    __syncthreads();
    int v = x;
    for (int off = 1; off < 1024; off <<= 1) {
        int tt = (t >= off) ? sm[t - off] : 0;
        __syncthreads();
        v += tt;
        sm[t] = v;
        __syncthreads();
    }
    if (t < nb) bsum[t] = v - x;
}

__global__ __launch_bounds__(256) void k_scan3g(int* __restrict__ offs,
                                                const int* __restrict__ bsum) {
    int i = blockIdx.x * 256 + threadIdx.x;
    offs[i] += bsum[blockIdx.x];
}

// Partition: scatter packed (src | dstlow<<17, coef) into bucket-major order.
__global__ __launch_bounds__(256) void k_part(const int* __restrict__ ei,
                                              const float* __restrict__ dinv,
                                              const int* __restrict__ offs,
                                              uint2* __restrict__ part) {
    __shared__ int cur[NBUK];
    int blk = blockIdx.x;
    for (int b = threadIdx.x; b < NBUK; b += 256) cur[b] = offs[b * PBLK + blk];
    __syncthreads();
    int base = blk * CHUNK;
    for (int k = threadIdx.x; k < CHUNK; k += 256) {
        int s = ei[base + k];
        int d = ei[NE + base + k];
        float c = dinv[s] * dinv[d];
        int pos = atomicAdd(&cur[d >> 8], 1);
        uint2 p;
        p.x = (unsigned)s | ((unsigned)(d & 255) << 17);   // s < 2^17
        p.y = __float_as_uint(c);
        part[pos] = p;
    }
}

// Tiled fp32 GEMM: out[N,64] = A[N,K] @ W[K,64] (+bias). 64x64 tile, 256 thr,
// 4x4 outputs/thread. DUAL writes two copies (h and ori).
template<int K, bool DUAL, bool BIAS>
__global__ __launch_bounds__(256) void k_gemm(const float* __restrict__ A,
                                              const float* __restrict__ W,
                                              const float* __restrict__ bias,
                                              float* __restrict__ out0,
                                              float* __restrict__ out1)
{
    __shared__ float As[64][65];
    __shared__ float Ws[64][64];
    const int tid = threadIdx.x;
    const int tx = tid & 15, ty = tid >> 4;
    const int c0 = tx * 4, r0 = ty * 4;
    const int row0 = blockIdx.x * 64;
    float acc[4][4] = {};

    for (int kt = 0; kt < K / 64; ++kt) {
        #pragma unroll
        for (int q = 0; q < 4; ++q) {
            int vid = q * 256 + tid;
            int row = vid >> 4;
            int kq  = vid & 15;
            if (row0 + row < NN) {
                float4 v = *reinterpret_cast<const float4*>(
                    &A[(size_t)(row0 + row) * K + kt * 64 + kq * 4]);
                As[row][kq * 4 + 0] = v.x; As[row][kq * 4 + 1] = v.y;
                As[row][kq * 4 + 2] = v.z; As[row][kq * 4 + 3] = v.w;
            }
            *reinterpret_cast<float4*>(&Ws[row][kq * 4]) =
                *reinterpret_cast<const float4*>(&W[(size_t)(kt * 64 + row) * HF + kq * 4]);
        }
        __syncthreads();
        #pragma unroll 8
        for (int k = 0; k < 64; ++k) {
            float4 wv = *reinterpret_cast<const float4*>(&Ws[k][c0]);
            float a0 = As[r0 + 0][k], a1 = As[r0 + 1][k];
            float a2 = As[r0 + 2][k], a3 = As[r0 + 3][k];
            acc[0][0] += a0 * wv.x; acc[0][1] += a0 * wv.y; acc[0][2] += a0 * wv.z; acc[0][3] += a0 * wv.w;
            acc[1][0] += a1 * wv.x; acc[1][1] += a1 * wv.y; acc[1][2] += a1 * wv.z; acc[1][3] += a1 * wv.w;
            acc[2][0] += a2 * wv.x; acc[2][1] += a2 * wv.y; acc[2][2] += a2 * wv.z; acc[2][3] += a2 * wv.w;
            acc[3][0] += a3 * wv.x; acc[3][1] += a3 * wv.y; acc[3][2] += a3 * wv.z; acc[3][3] += a3 * wv.w;
        }
        __syncthreads();
    }

    float4 bv = make_float4(0.f, 0.f, 0.f, 0.f);
    if (BIAS) bv = *reinterpret_cast<const float4*>(&bias[c0]);
    #pragma unroll
    for (int i = 0; i < 4; ++i) {
        int r = row0 + r0 + i;
        if (r < NN) {
            float4 o = make_float4(acc[i][0] + bv.x, acc[i][1] + bv.y,
                                   acc[i][2] + bv.z, acc[i][3] + bv.w);
            *reinterpret_cast<float4*>(&out0[(size_t)r * HF + c0]) = o;
            if (DUAL)
                *reinterpret_cast<float4*>(&out1[(size_t)r * HF + c0]) = o;
        }
    }
}

// One block per bucket: LDS acc[256][64] = selfloop+bias, ds_add_f32 per edge,
// coalesced write-out with optional fused residual+LN+ReLU.
template<int FUSE_LN>
__global__ __launch_bounds__(512) void k_gatherb(const int* __restrict__ offs,
                                                 const uint2* __restrict__ part,
                                                 const float* __restrict__ dinv,
                                                 const float* __restrict__ hw,
                                                 const float* __restrict__ cb,
                                                 const float* __restrict__ ori,
                                                 const float* __restrict__ lnw,
                                                 const float* __restrict__ lnb,
                                                 float* __restrict__ out)
{
    __shared__ float acc[256][HF];               // 64 KB -> 2 blocks/CU
    const int b    = blockIdx.x;
    const int wid  = threadIdx.x >> 6;
    const int lane = threadIdx.x & 63;
    const int row0 = b << 8;
    const float cbl = cb[lane];

    for (int r = wid; r < 256; r += 8) {
        int row = row0 + r;
        if (row < NN) {
            float di = dinv[row];
            acc[r][lane] = hw[(size_t)row * HF + lane] * di * di + cbl;
        }
    }
    __syncthreads();

    const int start = offs[b * PBLK];
    const int end   = (b == NBUK - 1) ? NE : offs[(b + 1) * PBLK];
    for (int base = start + (wid << 6); base < end; base += 8 * 64) {
        int n = end - base;
        if (n > 64) n = 64;
        int   px = 0;
        float pc = 0.0f;
        if (lane < n) {
            uint2 p = part[base + lane];
            px = (int)p.x;
            pc = __uint_as_float(p.y);
        }
        int j = 0;
        for (; j + 4 <= n; j += 4) {
            int   x0 = __shfl(px, j),     x1 = __shfl(px, j + 1);
            int   x2 = __shfl(px, j + 2), x3 = __shfl(px, j + 3);
            float c0 = __shfl(pc, j),     c1 = __shfl(pc, j + 1);
            float c2 = __shfl(pc, j + 2), c3 = __shfl(pc, j + 3);
            float v0 = hw[(size_t)(x0 & 0x1FFFF) * HF + lane] * c0;
            float v1 = hw[(size_t)(x1 & 0x1FFFF) * HF + lane] * c1;
            float v2 = hw[(size_t)(x2 & 0x1FFFF) * HF + lane] * c2;
            float v3 = hw[(size_t)(x3 & 0x1FFFF) * HF + lane] * c3;
            atomicAdd(&acc[((unsigned)x0) >> 17][lane], v0);
            atomicAdd(&acc[((unsigned)x1) >> 17][lane], v1);
            atomicAdd(&acc[((unsigned)x2) >> 17][lane], v2);
            atomicAdd(&acc[((unsigned)x3) >> 17][lane], v3);
        }
        for (; j < n; ++j) {
            int   x0 = __shfl(px, j);
            float c0 = __shfl(pc, j);
            float v0 = hw[(size_t)(x0 & 0x1FFFF) * HF + lane] * c0;
            atomicAdd(&acc[((unsigned)x0) >> 17][lane], v0);
        }
    }
    __syncthreads();

    for (int r = wid; r < 256; r += 8) {
        int row = row0 + r;
        if (row >= NN) continue;
        float v = acc[r][lane];
        size_t idx = (size_t)row * HF + lane;
        if (FUSE_LN) {
            v += ori[idx];
            float s = v;
            #pragma unroll
            for (int off = 32; off > 0; off >>= 1) s += __shfl_xor(s, off);
            float mu = s * (1.0f / 64.0f);
            float d = v - mu;
            float q = d * d;
            #pragma unroll
            for (int off = 32; off > 0; off >>= 1) q += __shfl_xor(q, off);
            float y = d * rsqrtf(q * (1.0f / 64.0f) + EPSV) * lnw[lane] + lnb[lane];
            out[idx] = fmaxf(y, 0.0f);
        } else {
            out[idx] = v;
        }
    }
}

extern "C" void kernel_launch(void* const* d_in, const int* in_sizes, int n_in,
                              void* d_out, int out_size, void* d_ws, size_t ws_size,
                              hipStream_t stream)
{
    const float* in_feat = (const float*)d_in[0];
    const int*   ei      = (const int*)d_in[1];   // [2][E]
    const float* lin_w   = (const float*)d_in[2];
    const float* lin_b   = (const float*)d_in[3];
    const float* conv_w  = (const float*)d_in[4];
    const float* conv_b  = (const float*)d_in[5];
    const float* ln_w    = (const float*)d_in[6]; // [3][64]
    const float* ln_b    = (const float*)d_in[7];
    float* out = (float*)d_out;
    float* ws  = (float*)d_ws;

    // Workspace (~92 MB): dinv | cnt | bh | offs | bsum | part | h | ori | hw
    float* dinv = ws;                          // NNP floats
    int*   cnt  = (int*)(ws + NNP);            // NNP
    int*   bh   = cnt + NNP;                   // SCN
    int*   offs = bh + SCN;                    // SCN
    int*   bsum = offs + SCN;                  // 1024
    uint2* part = (uint2*)(bsum + 1024);       // NE uint2 (8B aligned: even #ints)
    float* h    = (float*)(part + NE);         // NN*HF
    float* ori  = h + (size_t)NN * HF;         // NN*HF
    float* hw   = ori + (size_t)NN * HF;       // NN*HF

    // ---- degree + dinv ----
    k_zero<<<NNP / 256, 256, 0, stream>>>(cnt);
    k_hist<<<NE / 256, 256, 0, stream>>>(ei, cnt);
    k_dinv<<<NNP / 256, 256, 0, stream>>>(cnt, dinv);

    // ---- bucket partition (dst>>8) with per-edge coef ----
    k_bhist<<<PBLK, 256, 0, stream>>>(ei, bh);
    k_scan1g<<<SCN / 256, 256, 0, stream>>>(bh, offs, bsum);
    k_scan2g<<<1, 1024, 0, stream>>>(bsum, SCN / 256);
    k_scan3g<<<SCN / 256, 256, 0, stream>>>(offs, bsum);
    k_part<<<PBLK, 256, 0, stream>>>(ei, dinv, offs, part);

    // ---- h = ori = in_feat @ lin_w + lin_b ----
    k_gemm<128, true, true><<<(NN + 63) / 64, 256, 0, stream>>>(
        in_feat, lin_w, lin_b, h, ori);

    // ---- 3 propagation steps ----
    for (int it = 0; it < 3; ++it) {
        k_gemm<64, false, false><<<(NN + 63) / 64, 256, 0, stream>>>(
            h, conv_w, nullptr, hw, nullptr);
        if (it < 2) {
            k_gatherb<1><<<NBUK, 512, 0, stream>>>(
                offs, part, dinv, hw, conv_b, ori,
                ln_w + (it + 1) * HF, ln_b + (it + 1) * HF, h);
        } else {
            k_gatherb<0><<<NBUK, 512, 0, stream>>>(
                offs, part, dinv, hw, conv_b, nullptr, nullptr, nullptr, out);
        }
    }
}

// Round 5
// 516.923 us; speedup vs baseline: 4.9246x; 4.9246x over previous
//
#include <hip/hip_runtime.h>

// GCN_56521769616159 R5: hybrid of R2+R3 learnings.
//  - R2 showed: per-row wave gather (100k waves) hides random-gather latency;
//    exact CSR fill via global scatter costs 106MB HBM writes (16x amp).
//  - R3/R4 showed: bucket-LDS gather has only 3128 waves -> 28% occupancy,
//    772us (latency-bound); but bucket partition writes are cheap (~25MB).
//  => coarse bucket partition (dst>>8) -> bucket-local counting sort to exact
//     CSR (writes localized to 32KB spans) -> per-row wave gather with
//     precomputed coef in the edge record (no random dinv reads).

static constexpr int NN    = 100000;
static constexpr int NE    = 1600000;
static constexpr int HF    = 64;
static constexpr int NNP   = 100352;        // NN padded to 256 (392 blocks)
static constexpr int NBUK  = 391;           // ceil(NN/256): bucket = dst>>8
static constexpr int PBLK  = 512;           // partition blocks
static constexpr int CHUNK = NE / PBLK;     // 3125 edges per partition block
static constexpr int SCN   = NBUK * PBLK;   // 200192 = 782*256 exactly
#define EPSV 1e-5f

__global__ __launch_bounds__(256) void k_zero(int* __restrict__ c) {
    int i = blockIdx.x * 256 + threadIdx.x;
    if (i < NN) c[i] = 0;
}

// Per-node in-degree (dst histogram, no self-loop).
__global__ __launch_bounds__(256) void k_hist(const int* __restrict__ ei,
                                              int* __restrict__ cnt) {
    int e = blockIdx.x * 256 + threadIdx.x;
    if (e < NE) atomicAdd(&cnt[ei[NE + e]], 1);
}

__global__ __launch_bounds__(256) void k_dinv(const int* __restrict__ cnt,
                                              float* __restrict__ dinv) {
    int i = blockIdx.x * 256 + threadIdx.x;
    if (i < NN) dinv[i] = rsqrtf((float)cnt[i] + 1.0f);  // +1 self-loop
}

// ---- coarse bucket partition (from R3; measured cheap) ----

__global__ __launch_bounds__(256) void k_bhist(const int* __restrict__ ei,
                                               int* __restrict__ bh) {
    __shared__ int cnts[NBUK];
    for (int b = threadIdx.x; b < NBUK; b += 256) cnts[b] = 0;
    __syncthreads();
    int base = blockIdx.x * CHUNK;
    for (int k = threadIdx.x; k < CHUNK; k += 256)
        atomicAdd(&cnts[ei[NE + base + k] >> 8], 1);
    __syncthreads();
    for (int b = threadIdx.x; b < NBUK; b += 256)
        bh[blockIdx.x * NBUK + b] = cnts[b];
}

// Exclusive scan of bh in bucket-major order -> offs[buk*PBLK + blk].
__global__ __launch_bounds__(256) void k_scan1g(const int* __restrict__ bh,
                                                int* __restrict__ offs,
                                                int* __restrict__ bsum) {
    __shared__ int sm[256];
    int i = blockIdx.x * 256 + threadIdx.x;      // i < SCN always
    int buk = i >> 9, blk = i & (PBLK - 1);
    int x = bh[blk * NBUK + buk];
    sm[threadIdx.x] = x;
    __syncthreads();
    int v = x;
    for (int off = 1; off < 256; off <<= 1) {
        int t = (threadIdx.x >= (unsigned)off) ? sm[threadIdx.x - off] : 0;
        __syncthreads();
        v += t;
        sm[threadIdx.x] = v;
        __syncthreads();
    }
    offs[i] = v - x;
    if (threadIdx.x == 255) bsum[blockIdx.x] = v;
}

__global__ __launch_bounds__(1024) void k_scan2g(int* __restrict__ bsum, int nb) {
    __shared__ int sm[1024];
    int t = threadIdx.x;
    int x = (t < nb) ? bsum[t] : 0;
    sm[t] = x;
    __syncthreads();
    int v = x;
    for (int off = 1; off < 1024; off <<= 1) {
        int tt = (t >= off) ? sm[t - off] : 0;
        __syncthreads();
        v += tt;
        sm[t] = v;
        __syncthreads();
    }
    if (t < nb) bsum[t] = v - x;
}

__global__ __launch_bounds__(256) void k_scan3g(int* __restrict__ offs,
                                                const int* __restrict__ bsum) {
    int i = blockIdx.x * 256 + threadIdx.x;
    offs[i] += bsum[blockIdx.x];
}

// Partition: scatter packed (src | dstlow<<17, coef) into bucket-major order.
__global__ __launch_bounds__(256) void k_part(const int* __restrict__ ei,
                                              const float* __restrict__ dinv,
                                              const int* __restrict__ offs,
                                              uint2* __restrict__ part) {
    __shared__ int cur[NBUK];
    int blk = blockIdx.x;
    for (int b = threadIdx.x; b < NBUK; b += 256) cur[b] = offs[b * PBLK + blk];
    __syncthreads();
    int base = blk * CHUNK;
    for (int k = threadIdx.x; k < CHUNK; k += 256) {
        int s = ei[base + k];
        int d = ei[NE + base + k];
        float c = dinv[s] * dinv[d];
        int pos = atomicAdd(&cur[d >> 8], 1);
        uint2 p;
        p.x = (unsigned)s | ((unsigned)(d & 255) << 17);   // s < 2^17
        p.y = __float_as_uint(c);
        part[pos] = p;
    }
}

// ---- per-node exclusive scan (cnt -> rowp), rowp[NN]=NE ----

__global__ __launch_bounds__(256) void k_scanA1(const int* __restrict__ cnt,
                                                int* __restrict__ rowp,
                                                int* __restrict__ bsum) {
    __shared__ int sm[256];
    int i = blockIdx.x * 256 + threadIdx.x;
    int x = (i < NN) ? cnt[i] : 0;
    sm[threadIdx.x] = x;
    __syncthreads();
    int v = x;
    for (int off = 1; off < 256; off <<= 1) {
        int t = (threadIdx.x >= (unsigned)off) ? sm[threadIdx.x - off] : 0;
        __syncthreads();
        v += t;
        sm[threadIdx.x] = v;
        __syncthreads();
    }
    rowp[i] = v - x;                    // i < NNP always (grid = NNP/256)
    if (threadIdx.x == 255) bsum[blockIdx.x] = v;
}

__global__ __launch_bounds__(256) void k_scanA3(int* __restrict__ rowp,
                                                const int* __restrict__ bsum) {
    int i = blockIdx.x * 256 + threadIdx.x;
    rowp[i] += bsum[blockIdx.x];
    if (i == NN) rowp[NN] = NE;         // total (bsum prefix ends at NE anyway)
}

// ---- bucket-local counting sort: part (bucket-major) -> es2 (exact CSR) ----
// Bucket b's part span and CSR span are identical: [rowp[b*256], rowp[(b+1)*256]).
// Writes land within that ~32KB span -> L2 write coalescing, ~13MB HBM.
__global__ __launch_bounds__(256) void k_fine(const uint2* __restrict__ part,
                                              const int* __restrict__ rowp,
                                              uint2* __restrict__ es2) {
    __shared__ int cur[256];
    int b = blockIdx.x;
    int row0 = b << 8;
    int r1 = (b + 1) << 8; if (r1 > NN) r1 = NN;
    cur[threadIdx.x] = (row0 + (int)threadIdx.x < NN) ? rowp[row0 + threadIdx.x] : 0;
    __syncthreads();
    int bstart = rowp[row0], bend = rowp[r1];
    for (int k = bstart + threadIdx.x; k < bend; k += 256) {
        uint2 p = part[k];
        int dl = (int)(p.x >> 17);
        int pos = atomicAdd(&cur[dl], 1);
        es2[pos] = make_uint2(p.x & 0x1FFFF, p.y);
    }
}

// Tiled fp32 GEMM: out[N,64] = A[N,K] @ W[K,64] (+bias). 64x64 tile, 256 thr,
// 4x4 outputs/thread. DUAL writes two copies (h and ori).
template<int K, bool DUAL, bool BIAS>
__global__ __launch_bounds__(256) void k_gemm(const float* __restrict__ A,
                                              const float* __restrict__ W,
                                              const float* __restrict__ bias,
                                              float* __restrict__ out0,
                                              float* __restrict__ out1)
{
    __shared__ float As[64][65];
    __shared__ float Ws[64][64];
    const int tid = threadIdx.x;
    const int tx = tid & 15, ty = tid >> 4;
    const int c0 = tx * 4, r0 = ty * 4;
    const int row0 = blockIdx.x * 64;
    float acc[4][4] = {};

    for (int kt = 0; kt < K / 64; ++kt) {
        #pragma unroll
        for (int q = 0; q < 4; ++q) {
            int vid = q * 256 + tid;
            int row = vid >> 4;
            int kq  = vid & 15;
            if (row0 + row < NN) {
                float4 v = *reinterpret_cast<const float4*>(
                    &A[(size_t)(row0 + row) * K + kt * 64 + kq * 4]);
                As[row][kq * 4 + 0] = v.x; As[row][kq * 4 + 1] = v.y;
                As[row][kq * 4 + 2] = v.z; As[row][kq * 4 + 3] = v.w;
            }
            *reinterpret_cast<float4*>(&Ws[row][kq * 4]) =
                *reinterpret_cast<const float4*>(&W[(size_t)(kt * 64 + row) * HF + kq * 4]);
        }
        __syncthreads();
        #pragma unroll 8
        for (int k = 0; k < 64; ++k) {
            float4 wv = *reinterpret_cast<const float4*>(&Ws[k][c0]);
            float a0 = As[r0 + 0][k], a1 = As[r0 + 1][k];
            float a2 = As[r0 + 2][k], a3 = As[r0 + 3][k];
            acc[0][0] += a0 * wv.x; acc[0][1] += a0 * wv.y; acc[0][2] += a0 * wv.z; acc[0][3] += a0 * wv.w;
            acc[1][0] += a1 * wv.x; acc[1][1] += a1 * wv.y; acc[1][2] += a1 * wv.z; acc[1][3] += a1 * wv.w;
            acc[2][0] += a2 * wv.x; acc[2][1] += a2 * wv.y; acc[2][2] += a2 * wv.z; acc[2][3] += a2 * wv.w;
            acc[3][0] += a3 * wv.x; acc[3][1] += a3 * wv.y; acc[3][2] += a3 * wv.z; acc[3][3] += a3 * wv.w;
        }
        __syncthreads();
    }

    float4 bv = make_float4(0.f, 0.f, 0.f, 0.f);
    if (BIAS) bv = *reinterpret_cast<const float4*>(&bias[c0]);
    #pragma unroll
    for (int i = 0; i < 4; ++i) {
        int r = row0 + r0 + i;
        if (r < NN) {
            float4 o = make_float4(acc[i][0] + bv.x, acc[i][1] + bv.y,
                                   acc[i][2] + bv.z, acc[i][3] + bv.w);
            *reinterpret_cast<float4*>(&out0[(size_t)r * HF + c0]) = o;
            if (DUAL)
                *reinterpret_cast<float4*>(&out1[(size_t)r * HF + c0]) = o;
        }
    }
}

// One wave per dst row: acc = selfloop+bias + sum coef*hw[src][lane] over the
// row's CSR edges (uint2 = (src,coef), one coalesced load per edge-lane).
// 8-wide unrolled random row loads for ILP. FUSE_LN: residual+LN+ReLU epilogue.
template<int FUSE_LN>
__global__ __launch_bounds__(256) void k_gather2(const int* __restrict__ rowp,
                                                 const uint2* __restrict__ es2,
                                                 const float* __restrict__ dinv,
                                                 const float* __restrict__ hw,
                                                 const float* __restrict__ cb,
                                                 const float* __restrict__ ori,
                                                 const float* __restrict__ lnw,
                                                 const float* __restrict__ lnb,
                                                 float* __restrict__ out)
{
    int row = blockIdx.x * 4 + (threadIdx.x >> 6);
    if (row >= NN) return;                       // wave-uniform
    int lane = threadIdx.x & 63;
    float dd = dinv[row];
    float acc = hw[(size_t)row * HF + lane] * dd * dd + cb[lane];

    int start = rowp[row], end = rowp[row + 1];
    for (int base = start; base < end; base += 64) {
        int n = end - base;
        if (n > 64) n = 64;
        int   sl = 0;
        float cl = 0.0f;
        if (lane < n) {
            uint2 p = es2[base + lane];
            sl = (int)p.x;
            cl = __uint_as_float(p.y);
        }
        int j = 0;
        for (; j + 8 <= n; j += 8) {
            float v0 = hw[(size_t)__shfl(sl, j + 0) * HF + lane];
            float v1 = hw[(size_t)__shfl(sl, j + 1) * HF + lane];
            float v2 = hw[(size_t)__shfl(sl, j + 2) * HF + lane];
            float v3 = hw[(size_t)__shfl(sl, j + 3) * HF + lane];
            float v4 = hw[(size_t)__shfl(sl, j + 4) * HF + lane];
            float v5 = hw[(size_t)__shfl(sl, j + 5) * HF + lane];
            float v6 = hw[(size_t)__shfl(sl, j + 6) * HF + lane];
            float v7 = hw[(size_t)__shfl(sl, j + 7) * HF + lane];
            acc += v0 * __shfl(cl, j + 0) + v1 * __shfl(cl, j + 1)
                 + v2 * __shfl(cl, j + 2) + v3 * __shfl(cl, j + 3)
                 + v4 * __shfl(cl, j + 4) + v5 * __shfl(cl, j + 5)
                 + v6 * __shfl(cl, j + 6) + v7 * __shfl(cl, j + 7);
        }
        for (; j < n; ++j)
            acc += hw[(size_t)__shfl(sl, j) * HF + lane] * __shfl(cl, j);
    }

    size_t idx = (size_t)row * HF + lane;
    if (FUSE_LN) {
        float v = acc + ori[idx];
        float s = v;
        #pragma unroll
        for (int off = 32; off > 0; off >>= 1) s += __shfl_xor(s, off);
        float mu = s * (1.0f / 64.0f);
        float d = v - mu;
        float q = d * d;
        #pragma unroll
        for (int off = 32; off > 0; off >>= 1) q += __shfl_xor(q, off);
        float y = d * rsqrtf(q * (1.0f / 64.0f) + EPSV) * lnw[lane] + lnb[lane];
        out[idx] = fmaxf(y, 0.0f);
    } else {
        out[idx] = acc;
    }
}

extern "C" void kernel_launch(void* const* d_in, const int* in_sizes, int n_in,
                              void* d_out, int out_size, void* d_ws, size_t ws_size,
                              hipStream_t stream)
{
    const float* in_feat = (const float*)d_in[0];
    const int*   ei      = (const int*)d_in[1];   // [2][E]
    const float* lin_w   = (const float*)d_in[2];
    const float* lin_b   = (const float*)d_in[3];
    const float* conv_w  = (const float*)d_in[4];
    const float* conv_b  = (const float*)d_in[5];
    const float* ln_w    = (const float*)d_in[6]; // [3][64]
    const float* ln_b    = (const float*)d_in[7];
    float* out = (float*)d_out;
    float* ws  = (float*)d_ws;

    // Workspace (~105 MB):
    float* dinv = ws;                          // NNP floats
    int*   cnt  = (int*)(ws + NNP);            // NNP
    int*   rowp = cnt + NNP;                   // NNP (rowp[NN] = NE)
    int*   bh   = rowp + NNP;                  // SCN
    int*   offs = bh + SCN;                    // SCN
    int*   bsum = offs + SCN;                  // 1024 (reused by both scans)
    uint2* part = (uint2*)(bsum + 1024);       // NE uint2 (8B-aligned)
    uint2* es2  = part + NE;                   // NE uint2 (exact CSR, (src,coef))
    float* h    = (float*)(es2 + NE);          // NN*HF
    float* ori  = h + (size_t)NN * HF;         // NN*HF
    float* hw   = ori + (size_t)NN * HF;       // NN*HF

    // ---- degree + dinv ----
    k_zero<<<NNP / 256, 256, 0, stream>>>(cnt);
    k_hist<<<NE / 256, 256, 0, stream>>>(ei, cnt);
    k_dinv<<<NNP / 256, 256, 0, stream>>>(cnt, dinv);

    // ---- coarse bucket partition (dst>>8) with per-edge coef ----
    k_bhist<<<PBLK, 256, 0, stream>>>(ei, bh);
    k_scan1g<<<SCN / 256, 256, 0, stream>>>(bh, offs, bsum);
    k_scan2g<<<1, 1024, 0, stream>>>(bsum, SCN / 256);
    k_scan3g<<<SCN / 256, 256, 0, stream>>>(offs, bsum);
    k_part<<<PBLK, 256, 0, stream>>>(ei, dinv, offs, part);

    // ---- per-node rowp scan ----
    k_scanA1<<<NNP / 256, 256, 0, stream>>>(cnt, rowp, bsum);
    k_scan2g<<<1, 1024, 0, stream>>>(bsum, NNP / 256);
    k_scanA3<<<NNP / 256, 256, 0, stream>>>(rowp, bsum);

    // ---- bucket-local counting sort -> exact CSR ----
    k_fine<<<NBUK, 256, 0, stream>>>(part, rowp, es2);

    // ---- h = ori = in_feat @ lin_w + lin_b ----
    k_gemm<128, true, true><<<(NN + 63) / 64, 256, 0, stream>>>(
        in_feat, lin_w, lin_b, h, ori);

    // ---- 3 propagation steps ----
    for (int it = 0; it < 3; ++it) {
        k_gemm<64, false, false><<<(NN + 63) / 64, 256, 0, stream>>>(
            h, conv_w, nullptr, hw, nullptr);
        if (it < 2) {
            k_gather2<1><<<(NN + 3) / 4, 256, 0, stream>>>(
                rowp, es2, dinv, hw, conv_b, ori,
                ln_w + (it + 1) * HF, ln_b + (it + 1) * HF, h);
        } else {
            k_gather2<0><<<(NN + 3) / 4, 256, 0, stream>>>(
                rowp, es2, dinv, hw, conv_b, nullptr, nullptr, nullptr, out);
        }
    }
}

// Round 6
// 494.490 us; speedup vs baseline: 5.1480x; 1.0454x over previous
//
#include <hip/hip_runtime.h>

// GCN_56521769616159 R6: R5 + bf16 hw (gather operand). R5 counters: gather
// FETCH=207MB/pass (50% L2 miss, hw 25.6MB >> 4MB/XCD L2); gathers = 42% of
// 517us. bf16 halves row bytes AND working set -> higher L2 hit rate.
// Accumulation stays fp32; only the gathered rows are RNE-rounded to bf16.

static constexpr int NN    = 100000;
static constexpr int NE    = 1600000;
static constexpr int HF    = 64;
static constexpr int NNP   = 100352;        // NN padded to 256 (392 blocks)
static constexpr int NBUK  = 391;           // ceil(NN/256): bucket = dst>>8
static constexpr int PBLK  = 512;           // partition blocks
static constexpr int CHUNK = NE / PBLK;     // 3125 edges per partition block
static constexpr int SCN   = NBUK * PBLK;   // 200192 = 782*256 exactly
#define EPSV 1e-5f

static __device__ __forceinline__ unsigned short f2bf(float f) {
    unsigned u = __float_as_uint(f);
    u = (u + 0x7FFFu + ((u >> 16) & 1u)) >> 16;     // RNE
    return (unsigned short)u;
}
static __device__ __forceinline__ float bf2f(unsigned short h) {
    return __uint_as_float(((unsigned)h) << 16);
}

__global__ __launch_bounds__(256) void k_zero(int* __restrict__ c) {
    int i = blockIdx.x * 256 + threadIdx.x;
    if (i < NN) c[i] = 0;
}

// Per-node in-degree (dst histogram, no self-loop).
__global__ __launch_bounds__(256) void k_hist(const int* __restrict__ ei,
                                              int* __restrict__ cnt) {
    int e = blockIdx.x * 256 + threadIdx.x;
    if (e < NE) atomicAdd(&cnt[ei[NE + e]], 1);
}

__global__ __launch_bounds__(256) void k_dinv(const int* __restrict__ cnt,
                                              float* __restrict__ dinv) {
    int i = blockIdx.x * 256 + threadIdx.x;
    if (i < NN) dinv[i] = rsqrtf((float)cnt[i] + 1.0f);  // +1 self-loop
}

// ---- coarse bucket partition (dst>>8) ----

__global__ __launch_bounds__(256) void k_bhist(const int* __restrict__ ei,
                                               int* __restrict__ bh) {
    __shared__ int cnts[NBUK];
    for (int b = threadIdx.x; b < NBUK; b += 256) cnts[b] = 0;
    __syncthreads();
    int base = blockIdx.x * CHUNK;
    for (int k = threadIdx.x; k < CHUNK; k += 256)
        atomicAdd(&cnts[ei[NE + base + k] >> 8], 1);
    __syncthreads();
    for (int b = threadIdx.x; b < NBUK; b += 256)
        bh[blockIdx.x * NBUK + b] = cnts[b];
}

// Exclusive scan of bh in bucket-major order -> offs[buk*PBLK + blk].
__global__ __launch_bounds__(256) void k_scan1g(const int* __restrict__ bh,
                                                int* __restrict__ offs,
                                                int* __restrict__ bsum) {
    __shared__ int sm[256];
    int i = blockIdx.x * 256 + threadIdx.x;      // i < SCN always
    int buk = i >> 9, blk = i & (PBLK - 1);
    int x = bh[blk * NBUK + buk];
    sm[threadIdx.x] = x;
    __syncthreads();
    int v = x;
    for (int off = 1; off < 256; off <<= 1) {
        int t = (threadIdx.x >= (unsigned)off) ? sm[threadIdx.x - off] : 0;
        __syncthreads();
        v += t;
        sm[threadIdx.x] = v;
        __syncthreads();
    }
    offs[i] = v - x;
    if (threadIdx.x == 255) bsum[blockIdx.x] = v;
}

__global__ __launch_bounds__(1024) void k_scan2g(int* __restrict__ bsum, int nb) {
    __shared__ int sm[1024];
    int t = threadIdx.x;
    int x = (t < nb) ? bsum[t] : 0;
    sm[t] = x;
    __syncthreads();
    int v = x;
    for (int off = 1; off < 1024; off <<= 1) {
        int tt = (t >= off) ? sm[t - off] : 0;
        __syncthreads();
        v += tt;
        sm[t] = v;
        __syncthreads();
    }
    if (t < nb) bsum[t] = v - x;
}

__global__ __launch_bounds__(256) void k_scan3g(int* __restrict__ offs,
                                                const int* __restrict__ bsum) {
    int i = blockIdx.x * 256 + threadIdx.x;
    offs[i] += bsum[blockIdx.x];
}

// Partition: scatter packed (src | dstlow<<17, coef) into bucket-major order.
__global__ __launch_bounds__(256) void k_part(const int* __restrict__ ei,
                                              const float* __restrict__ dinv,
                                              const int* __restrict__ offs,
                                              uint2* __restrict__ part) {
    __shared__ int cur[NBUK];
    int blk = blockIdx.x;
    for (int b = threadIdx.x; b < NBUK; b += 256) cur[b] = offs[b * PBLK + blk];
    __syncthreads();
    int base = blk * CHUNK;
    for (int k = threadIdx.x; k < CHUNK; k += 256) {
        int s = ei[base + k];
        int d = ei[NE + base + k];
        float c = dinv[s] * dinv[d];
        int pos = atomicAdd(&cur[d >> 8], 1);
        uint2 p;
        p.x = (unsigned)s | ((unsigned)(d & 255) << 17);   // s < 2^17
        p.y = __float_as_uint(c);
        part[pos] = p;
    }
}

// ---- per-node exclusive scan (cnt -> rowp), rowp[NN]=NE ----

__global__ __launch_bounds__(256) void k_scanA1(const int* __restrict__ cnt,
                                                int* __restrict__ rowp,
                                                int* __restrict__ bsum) {
    __shared__ int sm[256];
    int i = blockIdx.x * 256 + threadIdx.x;
    int x = (i < NN) ? cnt[i] : 0;
    sm[threadIdx.x] = x;
    __syncthreads();
    int v = x;
    for (int off = 1; off < 256; off <<= 1) {
        int t = (threadIdx.x >= (unsigned)off) ? sm[threadIdx.x - off] : 0;
        __syncthreads();
        v += t;
        sm[threadIdx.x] = v;
        __syncthreads();
    }
    rowp[i] = v - x;                    // i < NNP always (grid = NNP/256)
    if (threadIdx.x == 255) bsum[blockIdx.x] = v;
}

__global__ __launch_bounds__(256) void k_scanA3(int* __restrict__ rowp,
                                                const int* __restrict__ bsum) {
    int i = blockIdx.x * 256 + threadIdx.x;
    rowp[i] += bsum[blockIdx.x];
    if (i == NN) rowp[NN] = NE;
}

// ---- bucket-local counting sort: part (bucket-major) -> es2 (exact CSR) ----
__global__ __launch_bounds__(256) void k_fine(const uint2* __restrict__ part,
                                              const int* __restrict__ rowp,
                                              uint2* __restrict__ es2) {
    __shared__ int cur[256];
    int b = blockIdx.x;
    int row0 = b << 8;
    int r1 = (b + 1) << 8; if (r1 > NN) r1 = NN;
    cur[threadIdx.x] = (row0 + (int)threadIdx.x < NN) ? rowp[row0 + threadIdx.x] : 0;
    __syncthreads();
    int bstart = rowp[row0], bend = rowp[r1];
    for (int k = bstart + threadIdx.x; k < bend; k += 256) {
        uint2 p = part[k];
        int dl = (int)(p.x >> 17);
        int pos = atomicAdd(&cur[dl], 1);
        es2[pos] = make_uint2(p.x & 0x1FFFF, p.y);
    }
}

// Tiled fp32 GEMM: out[N,64] = A[N,K] @ W[K,64] (+bias). 64x64 tile, 256 thr,
// 4x4 outputs/thread. DUAL writes two fp32 copies; OUTBF writes bf16 (ushort).
template<int K, bool DUAL, bool BIAS, bool OUTBF>
__global__ __launch_bounds__(256) void k_gemm(const float* __restrict__ A,
                                              const float* __restrict__ W,
                                              const float* __restrict__ bias,
                                              void* __restrict__ out0v,
                                              float* __restrict__ out1)
{
    __shared__ float As[64][65];
    __shared__ float Ws[64][64];
    const int tid = threadIdx.x;
    const int tx = tid & 15, ty = tid >> 4;
    const int c0 = tx * 4, r0 = ty * 4;
    const int row0 = blockIdx.x * 64;
    float acc[4][4] = {};

    for (int kt = 0; kt < K / 64; ++kt) {
        #pragma unroll
        for (int q = 0; q < 4; ++q) {
            int vid = q * 256 + tid;
            int row = vid >> 4;
            int kq  = vid & 15;
            if (row0 + row < NN) {
                float4 v = *reinterpret_cast<const float4*>(
                    &A[(size_t)(row0 + row) * K + kt * 64 + kq * 4]);
                As[row][kq * 4 + 0] = v.x; As[row][kq * 4 + 1] = v.y;
                As[row][kq * 4 + 2] = v.z; As[row][kq * 4 + 3] = v.w;
            }
            *reinterpret_cast<float4*>(&Ws[row][kq * 4]) =
                *reinterpret_cast<const float4*>(&W[(size_t)(kt * 64 + row) * HF + kq * 4]);
        }
        __syncthreads();
        #pragma unroll 8
        for (int k = 0; k < 64; ++k) {
            float4 wv = *reinterpret_cast<const float4*>(&Ws[k][c0]);
            float a0 = As[r0 + 0][k], a1 = As[r0 + 1][k];
            float a2 = As[r0 + 2][k], a3 = As[r0 + 3][k];
            acc[0][0] += a0 * wv.x; acc[0][1] += a0 * wv.y; acc[0][2] += a0 * wv.z; acc[0][3] += a0 * wv.w;
            acc[1][0] += a1 * wv.x; acc[1][1] += a1 * wv.y; acc[1][2] += a1 * wv.z; acc[1][3] += a1 * wv.w;
            acc[2][0] += a2 * wv.x; acc[2][1] += a2 * wv.y; acc[2][2] += a2 * wv.z; acc[2][3] += a2 * wv.w;
            acc[3][0] += a3 * wv.x; acc[3][1] += a3 * wv.y; acc[3][2] += a3 * wv.z; acc[3][3] += a3 * wv.w;
        }
        __syncthreads();
    }

    float4 bv = make_float4(0.f, 0.f, 0.f, 0.f);
    if (BIAS) bv = *reinterpret_cast<const float4*>(&bias[c0]);
    #pragma unroll
    for (int i = 0; i < 4; ++i) {
        int r = row0 + r0 + i;
        if (r < NN) {
            float4 o = make_float4(acc[i][0] + bv.x, acc[i][1] + bv.y,
                                   acc[i][2] + bv.z, acc[i][3] + bv.w);
            if (OUTBF) {
                ushort4 ob;
                ob.x = f2bf(o.x); ob.y = f2bf(o.y);
                ob.z = f2bf(o.z); ob.w = f2bf(o.w);
                *reinterpret_cast<ushort4*>(
                    &((unsigned short*)out0v)[(size_t)r * HF + c0]) = ob;
            } else {
                *reinterpret_cast<float4*>(&((float*)out0v)[(size_t)r * HF + c0]) = o;
                if (DUAL)
                    *reinterpret_cast<float4*>(&out1[(size_t)r * HF + c0]) = o;
            }
        }
    }
}

// One wave per dst row: acc = selfloop+bias + sum coef*bf2f(hw16[src][lane]).
// uint2 edge record = (src, coef). 8-wide unrolled random row loads for ILP.
template<int FUSE_LN>
__global__ __launch_bounds__(256) void k_gather2(const int* __restrict__ rowp,
                                                 const uint2* __restrict__ es2,
                                                 const float* __restrict__ dinv,
                                                 const unsigned short* __restrict__ hw16,
                                                 const float* __restrict__ cb,
                                                 const float* __restrict__ ori,
                                                 const float* __restrict__ lnw,
                                                 const float* __restrict__ lnb,
                                                 float* __restrict__ out)
{
    int row = blockIdx.x * 4 + (threadIdx.x >> 6);
    if (row >= NN) return;                       // wave-uniform
    int lane = threadIdx.x & 63;
    float dd = dinv[row];
    float acc = bf2f(hw16[(size_t)row * HF + lane]) * dd * dd + cb[lane];

    int start = rowp[row], end = rowp[row + 1];
    for (int base = start; base < end; base += 64) {
        int n = end - base;
        if (n > 64) n = 64;
        int   sl = 0;
        float cl = 0.0f;
        if (lane < n) {
            uint2 p = es2[base + lane];
            sl = (int)p.x;
            cl = __uint_as_float(p.y);
        }
        int j = 0;
        for (; j + 8 <= n; j += 8) {
            float v0 = bf2f(hw16[(size_t)__shfl(sl, j + 0) * HF + lane]);
            float v1 = bf2f(hw16[(size_t)__shfl(sl, j + 1) * HF + lane]);
            float v2 = bf2f(hw16[(size_t)__shfl(sl, j + 2) * HF + lane]);
            float v3 = bf2f(hw16[(size_t)__shfl(sl, j + 3) * HF + lane]);
            float v4 = bf2f(hw16[(size_t)__shfl(sl, j + 4) * HF + lane]);
            float v5 = bf2f(hw16[(size_t)__shfl(sl, j + 5) * HF + lane]);
            float v6 = bf2f(hw16[(size_t)__shfl(sl, j + 6) * HF + lane]);
            float v7 = bf2f(hw16[(size_t)__shfl(sl, j + 7) * HF + lane]);
            acc += v0 * __shfl(cl, j + 0) + v1 * __shfl(cl, j + 1)
                 + v2 * __shfl(cl, j + 2) + v3 * __shfl(cl, j + 3)
                 + v4 * __shfl(cl, j + 4) + v5 * __shfl(cl, j + 5)
                 + v6 * __shfl(cl, j + 6) + v7 * __shfl(cl, j + 7);
        }
        for (; j < n; ++j)
            acc += bf2f(hw16[(size_t)__shfl(sl, j) * HF + lane]) * __shfl(cl, j);
    }

    size_t idx = (size_t)row * HF + lane;
    if (FUSE_LN) {
        float v = acc + ori[idx];
        float s = v;
        #pragma unroll
        for (int off = 32; off > 0; off >>= 1) s += __shfl_xor(s, off);
        float mu = s * (1.0f / 64.0f);
        float d = v - mu;
        float q = d * d;
        #pragma unroll
        for (int off = 32; off > 0; off >>= 1) q += __shfl_xor(q, off);
        float y = d * rsqrtf(q * (1.0f / 64.0f) + EPSV) * lnw[lane] + lnb[lane];
        out[idx] = fmaxf(y, 0.0f);
    } else {
        out[idx] = acc;
    }
}

extern "C" void kernel_launch(void* const* d_in, const int* in_sizes, int n_in,
                              void* d_out, int out_size, void* d_ws, size_t ws_size,
                              hipStream_t stream)
{
    const float* in_feat = (const float*)d_in[0];
    const int*   ei      = (const int*)d_in[1];   // [2][E]
    const float* lin_w   = (const float*)d_in[2];
    const float* lin_b   = (const float*)d_in[3];
    const float* conv_w  = (const float*)d_in[4];
    const float* conv_b  = (const float*)d_in[5];
    const float* ln_w    = (const float*)d_in[6]; // [3][64]
    const float* ln_b    = (const float*)d_in[7];
    float* out = (float*)d_out;
    float* ws  = (float*)d_ws;

    // Workspace (~100 MB):
    float* dinv = ws;                          // NNP floats
    int*   cnt  = (int*)(ws + NNP);            // NNP
    int*   rowp = cnt + NNP;                   // NNP (rowp[NN] = NE)
    int*   bh   = rowp + NNP;                  // SCN
    int*   offs = bh + SCN;                    // SCN
    int*   bsum = offs + SCN;                  // 1024 (reused by both scans)
    uint2* part = (uint2*)(bsum + 1024);       // NE uint2 (8B-aligned)
    uint2* es2  = part + NE;                   // NE uint2 (exact CSR, (src,coef))
    float* h    = (float*)(es2 + NE);          // NN*HF fp32
    float* ori  = h + (size_t)NN * HF;         // NN*HF fp32
    unsigned short* hw16 = (unsigned short*)(ori + (size_t)NN * HF);  // NN*HF bf16

    // ---- degree + dinv ----
    k_zero<<<NNP / 256, 256, 0, stream>>>(cnt);
    k_hist<<<NE / 256, 256, 0, stream>>>(ei, cnt);
    k_dinv<<<NNP / 256, 256, 0, stream>>>(cnt, dinv);

    // ---- coarse bucket partition (dst>>8) with per-edge coef ----
    k_bhist<<<PBLK, 256, 0, stream>>>(ei, bh);
    k_scan1g<<<SCN / 256, 256, 0, stream>>>(bh, offs, bsum);
    k_scan2g<<<1, 1024, 0, stream>>>(bsum, SCN / 256);
    k_scan3g<<<SCN / 256, 256, 0, stream>>>(offs, bsum);
    k_part<<<PBLK, 256, 0, stream>>>(ei, dinv, offs, part);

    // ---- per-node rowp scan ----
    k_scanA1<<<NNP / 256, 256, 0, stream>>>(cnt, rowp, bsum);
    k_scan2g<<<1, 1024, 0, stream>>>(bsum, NNP / 256);
    k_scanA3<<<NNP / 256, 256, 0, stream>>>(rowp, bsum);

    // ---- bucket-local counting sort -> exact CSR ----
    k_fine<<<NBUK, 256, 0, stream>>>(part, rowp, es2);

    // ---- h = ori = in_feat @ lin_w + lin_b (fp32) ----
    k_gemm<128, true, true, false><<<(NN + 63) / 64, 256, 0, stream>>>(
        in_feat, lin_w, lin_b, h, ori);

    // ---- 3 propagation steps ----
    for (int it = 0; it < 3; ++it) {
        // hw16 = bf16(h @ conv_w)
        k_gemm<64, false, false, true><<<(NN + 63) / 64, 256, 0, stream>>>(
            h, conv_w, nullptr, hw16, nullptr);
        if (it < 2) {
            k_gather2<1><<<(NN + 3) / 4, 256, 0, stream>>>(
                rowp, es2, dinv, hw16, conv_b, ori,
                ln_w + (it + 1) * HF, ln_b + (it + 1) * HF, h);
        } else {
            k_gather2<0><<<(NN + 3) / 4, 256, 0, stream>>>(
                rowp, es2, dinv, hw16, conv_b, nullptr, nullptr, nullptr, out);
        }
    }
}

// Round 7
// 486.644 us; speedup vs baseline: 5.2310x; 1.0161x over previous
//
#include <hip/hip_runtime.h>

// GCN_56521769616159 R7: R6 + (a) W=2 gather: lanes 0-31/32-63 process
// even/odd edges over uint (2xbf16) columns -> ~1.8x fewer per-edge
// instructions (R6 showed gather is VALU/issue-bound: FETCH halved 207->106MB
// but dur only 72->66us, VALUBusy 48%); (b) kernel-count 21->13 via fused
// histograms and fused scan chains (launch-gap overhead ~130us of 494us).

static constexpr int NN    = 100000;
static constexpr int NE    = 1600000;
static constexpr int HF    = 64;
static constexpr int NNP   = 100352;        // NN padded to 256
static constexpr int NBUK  = 391;           // ceil(NN/256): bucket = dst>>8
static constexpr int PBLK  = 512;           // partition blocks
static constexpr int CHUNK = NE / PBLK;     // 3125 edges per partition block
static constexpr int SCN   = NBUK * PBLK;   // 200192 = 782*256
static constexpr int GB    = SCN / 256;     // 782 scan blocks (bucket scan)
static constexpr int AB    = NNP / 256;     // 392 scan blocks (node scan)
#define EPSV 1e-5f

static __device__ __forceinline__ unsigned short f2bf(float f) {
    unsigned u = __float_as_uint(f);
    u = (u + 0x7FFFu + ((u >> 16) & 1u)) >> 16;     // RNE
    return (unsigned short)u;
}

__global__ __launch_bounds__(256) void k_zero(int* __restrict__ c) {
    int i = blockIdx.x * 256 + threadIdx.x;
    if (i < NN) c[i] = 0;
}

// Fused: per-node in-degree (global atomics) + per-block bucket histogram.
__global__ __launch_bounds__(256) void k_hist2(const int* __restrict__ ei,
                                               int* __restrict__ cnt,
                                               int* __restrict__ bh) {
    __shared__ int cnts[NBUK];
    for (int b = threadIdx.x; b < NBUK; b += 256) cnts[b] = 0;
    __syncthreads();
    int base = blockIdx.x * CHUNK;
    for (int k = threadIdx.x; k < CHUNK; k += 256) {
        int d = ei[NE + base + k];
        atomicAdd(&cnt[d], 1);
        atomicAdd(&cnts[d >> 8], 1);
    }
    __syncthreads();
    for (int b = threadIdx.x; b < NBUK; b += 256)
        bh[blockIdx.x * NBUK + b] = cnts[b];
}

// Fused scan stage 1: blocks [0,GB) scan bh (bucket-major) -> offs/bsum;
// blocks [GB,GB+AB) scan cnt -> rowp/bsumA, and compute dinv.
__global__ __launch_bounds__(256) void k_scanB1(const int* __restrict__ bh,
                                                int* __restrict__ offs,
                                                const int* __restrict__ cnt,
                                                int* __restrict__ rowp,
                                                float* __restrict__ dinv,
                                                int* __restrict__ bsum,
                                                int* __restrict__ bsumA) {
    __shared__ int sm[256];
    int blk = blockIdx.x;
    int x;
    int i;
    if (blk < GB) {
        i = blk * 256 + threadIdx.x;
        int buk = i >> 9, b2 = i & (PBLK - 1);
        x = bh[b2 * NBUK + buk];
    } else {
        i = (blk - GB) * 256 + threadIdx.x;
        x = (i < NN) ? cnt[i] : 0;
        if (i < NN) dinv[i] = rsqrtf((float)x + 1.0f);  // +1 self-loop
    }
    sm[threadIdx.x] = x;
    __syncthreads();
    int v = x;
    for (int off = 1; off < 256; off <<= 1) {
        int t = (threadIdx.x >= (unsigned)off) ? sm[threadIdx.x - off] : 0;
        __syncthreads();
        v += t;
        sm[threadIdx.x] = v;
        __syncthreads();
    }
    if (blk < GB) {
        offs[i] = v - x;
        if (threadIdx.x == 255) bsum[blk] = v;
    } else {
        rowp[i] = v - x;
        if (threadIdx.x == 255) bsumA[blk - GB] = v;
    }
}

// Fused scan stage 2: exclusive-scan bsum[GB] then bsumA[AB], one block.
__global__ __launch_bounds__(1024) void k_scanB2(int* __restrict__ bsum,
                                                 int* __restrict__ bsumA) {
    __shared__ int sm[1024];
    for (int pass = 0; pass < 2; ++pass) {
        int* arr = pass ? bsumA : bsum;
        int nb   = pass ? AB : GB;
        int t = threadIdx.x;
        int x = (t < nb) ? arr[t] : 0;
        sm[t] = x;
        __syncthreads();
        int v = x;
        for (int off = 1; off < 1024; off <<= 1) {
            int tt = (t >= off) ? sm[t - off] : 0;
            __syncthreads();
            v += tt;
            sm[t] = v;
            __syncthreads();
        }
        if (t < nb) arr[t] = v - x;
        __syncthreads();
    }
}

// Fused scan stage 3: add block offsets back; set rowp[NN]=NE.
__global__ __launch_bounds__(256) void k_scanB3(int* __restrict__ offs,
                                                int* __restrict__ rowp,
                                                const int* __restrict__ bsum,
                                                const int* __restrict__ bsumA) {
    int blk = blockIdx.x;
    if (blk < GB) {
        int i = blk * 256 + threadIdx.x;
        offs[i] += bsum[blk];
    } else {
        int i = (blk - GB) * 256 + threadIdx.x;
        rowp[i] += bsumA[blk - GB];
        if (i == NN) rowp[NN] = NE;
    }
}

// Partition: scatter packed (src | dstlow<<17, coef) into bucket-major order.
__global__ __launch_bounds__(256) void k_part(const int* __restrict__ ei,
                                              const float* __restrict__ dinv,
                                              const int* __restrict__ offs,
                                              uint2* __restrict__ part) {
    __shared__ int cur[NBUK];
    int blk = blockIdx.x;
    for (int b = threadIdx.x; b < NBUK; b += 256) cur[b] = offs[b * PBLK + blk];
    __syncthreads();
    int base = blk * CHUNK;
    for (int k = threadIdx.x; k < CHUNK; k += 256) {
        int s = ei[base + k];
        int d = ei[NE + base + k];
        float c = dinv[s] * dinv[d];
        int pos = atomicAdd(&cur[d >> 8], 1);
        uint2 p;
        p.x = (unsigned)s | ((unsigned)(d & 255) << 17);   // s < 2^17
        p.y = __float_as_uint(c);
        part[pos] = p;
    }
}

// Bucket-local counting sort: part (bucket-major) -> es2 (exact CSR).
__global__ __launch_bounds__(256) void k_fine(const uint2* __restrict__ part,
                                              const int* __restrict__ rowp,
                                              uint2* __restrict__ es2) {
    __shared__ int cur[256];
    int b = blockIdx.x;
    int row0 = b << 8;
    int r1 = (b + 1) << 8; if (r1 > NN) r1 = NN;
    cur[threadIdx.x] = (row0 + (int)threadIdx.x < NN) ? rowp[row0 + threadIdx.x] : 0;
    __syncthreads();
    int bstart = rowp[row0], bend = rowp[r1];
    for (int k = bstart + threadIdx.x; k < bend; k += 256) {
        uint2 p = part[k];
        int dl = (int)(p.x >> 17);
        int pos = atomicAdd(&cur[dl], 1);
        es2[pos] = make_uint2(p.x & 0x1FFFF, p.y);
    }
}

// Tiled fp32 GEMM: out[N,64] = A[N,K] @ W[K,64] (+bias). 64x64 tile, 256 thr,
// 4x4 outputs/thread. DUAL writes two fp32 copies; OUTBF writes bf16 (ushort).
template<int K, bool DUAL, bool BIAS, bool OUTBF>
__global__ __launch_bounds__(256) void k_gemm(const float* __restrict__ A,
                                              const float* __restrict__ W,
                                              const float* __restrict__ bias,
                                              void* __restrict__ out0v,
                                              float* __restrict__ out1)
{
    __shared__ float As[64][65];
    __shared__ float Ws[64][64];
    const int tid = threadIdx.x;
    const int tx = tid & 15, ty = tid >> 4;
    const int c0 = tx * 4, r0 = ty * 4;
    const int row0 = blockIdx.x * 64;
    float acc[4][4] = {};

    for (int kt = 0; kt < K / 64; ++kt) {
        #pragma unroll
        for (int q = 0; q < 4; ++q) {
            int vid = q * 256 + tid;
            int row = vid >> 4;
            int kq  = vid & 15;
            if (row0 + row < NN) {
                float4 v = *reinterpret_cast<const float4*>(
                    &A[(size_t)(row0 + row) * K + kt * 64 + kq * 4]);
                As[row][kq * 4 + 0] = v.x; As[row][kq * 4 + 1] = v.y;
                As[row][kq * 4 + 2] = v.z; As[row][kq * 4 + 3] = v.w;
            }
            *reinterpret_cast<float4*>(&Ws[row][kq * 4]) =
                *reinterpret_cast<const float4*>(&W[(size_t)(kt * 64 + row) * HF + kq * 4]);
        }
        __syncthreads();
        #pragma unroll 8
        for (int k = 0; k < 64; ++k) {
            float4 wv = *reinterpret_cast<const float4*>(&Ws[k][c0]);
            float a0 = As[r0 + 0][k], a1 = As[r0 + 1][k];
            float a2 = As[r0 + 2][k], a3 = As[r0 + 3][k];
            acc[0][0] += a0 * wv.x; acc[0][1] += a0 * wv.y; acc[0][2] += a0 * wv.z; acc[0][3] += a0 * wv.w;
            acc[1][0] += a1 * wv.x; acc[1][1] += a1 * wv.y; acc[1][2] += a1 * wv.z; acc[1][3] += a1 * wv.w;
            acc[2][0] += a2 * wv.x; acc[2][1] += a2 * wv.y; acc[2][2] += a2 * wv.z; acc[2][3] += a2 * wv.w;
            acc[3][0] += a3 * wv.x; acc[3][1] += a3 * wv.y; acc[3][2] += a3 * wv.z; acc[3][3] += a3 * wv.w;
        }
        __syncthreads();
    }

    float4 bv = make_float4(0.f, 0.f, 0.f, 0.f);
    if (BIAS) bv = *reinterpret_cast<const float4*>(&bias[c0]);
    #pragma unroll
    for (int i = 0; i < 4; ++i) {
        int r = row0 + r0 + i;
        if (r < NN) {
            float4 o = make_float4(acc[i][0] + bv.x, acc[i][1] + bv.y,
                                   acc[i][2] + bv.z, acc[i][3] + bv.w);
            if (OUTBF) {
                ushort4 ob;
                ob.x = f2bf(o.x); ob.y = f2bf(o.y);
                ob.z = f2bf(o.z); ob.w = f2bf(o.w);
                *reinterpret_cast<ushort4*>(
                    &((unsigned short*)out0v)[(size_t)r * HF + c0]) = ob;
            } else {
                *reinterpret_cast<float4*>(&((float*)out0v)[(size_t)r * HF + c0]) = o;
                if (DUAL)
                    *reinterpret_cast<float4*>(&out1[(size_t)r * HF + c0]) = o;
            }
        }
    }
}

// W=2 gather: wave per dst row. hw16 viewed as uint[NN][32] (2xbf16 per uint).
// Lane l: half = l>>5 (even/odd edge), c2 = l&31 (column pair). Per 2 edges:
// 1 dword load + 2 bpermutes (index j+half) + unpack + 2 FMA. Halves combined
// via shfl_xor(32); epilogue float2 ops from lanes 0-31.
template<int FUSE_LN>
__global__ __launch_bounds__(256) void k_gather3(const int* __restrict__ rowp,
                                                 const uint2* __restrict__ es2,
                                                 const float* __restrict__ dinv,
                                                 const unsigned* __restrict__ hwu,
                                                 const float* __restrict__ cb,
                                                 const float* __restrict__ ori,
                                                 const float* __restrict__ lnw,
                                                 const float* __restrict__ lnb,
                                                 float* __restrict__ out)
{
    int row = blockIdx.x * 4 + (threadIdx.x >> 6);
    if (row >= NN) return;                       // wave-uniform
    const int lane = threadIdx.x & 63;
    const int half = lane >> 5;
    const int c2   = lane & 31;
    const float dd = dinv[row];

    float ax, ay;
    if (half == 0) {                             // self-loop + bias in half 0 only
        unsigned u = hwu[(size_t)row * 32 + c2];
        float2 cbv = reinterpret_cast<const float2*>(cb)[c2];
        float s2 = dd * dd;
        ax = fmaf(__uint_as_float(u << 16),        s2, cbv.x);
        ay = fmaf(__uint_as_float(u & 0xFFFF0000u), s2, cbv.y);
    } else {
        ax = 0.0f; ay = 0.0f;
    }

    const int start = rowp[row], end = rowp[row + 1];
    for (int base = start; base < end; base += 64) {
        int n = end - base;
        if (n > 64) n = 64;
        int   sl = 0;
        float cl = 0.0f;                          // coef=0 for invalid lanes: safe
        if (lane < n) {
            uint2 p = es2[base + lane];
            sl = (int)p.x;
            cl = __uint_as_float(p.y);
        }
        int j = 0;
        for (; j + 16 <= n; j += 16) {            // 16 edges: 8 loads in flight
            int   s0 = __shfl(sl, j +  0 + half), s1 = __shfl(sl, j +  2 + half);
            int   s2_ = __shfl(sl, j +  4 + half), s3 = __shfl(sl, j +  6 + half);
            int   s4 = __shfl(sl, j +  8 + half), s5 = __shfl(sl, j + 10 + half);
            int   s6 = __shfl(sl, j + 12 + half), s7 = __shfl(sl, j + 14 + half);
            float c0 = __shfl(cl, j +  0 + half), c1 = __shfl(cl, j +  2 + half);
            float c2_ = __shfl(cl, j +  4 + half), c3 = __shfl(cl, j +  6 + half);
            float c4 = __shfl(cl, j +  8 + half), c5 = __shfl(cl, j + 10 + half);
            float c6 = __shfl(cl, j + 12 + half), c7 = __shfl(cl, j + 14 + half);
            unsigned u0 = hwu[(size_t)s0 * 32 + c2];
            unsigned u1 = hwu[(size_t)s1 * 32 + c2];
            unsigned u2 = hwu[(size_t)s2_ * 32 + c2];
            unsigned u3 = hwu[(size_t)s3 * 32 + c2];
            unsigned u4 = hwu[(size_t)s4 * 32 + c2];
            unsigned u5 = hwu[(size_t)s5 * 32 + c2];
            unsigned u6 = hwu[(size_t)s6 * 32 + c2];
            unsigned u7 = hwu[(size_t)s7 * 32 + c2];
            ax += __uint_as_float(u0 << 16) * c0;  ay += __uint_as_float(u0 & 0xFFFF0000u) * c0;
            ax += __uint_as_float(u1 << 16) * c1;  ay += __uint_as_float(u1 & 0xFFFF0000u) * c1;
            ax += __uint_as_float(u2 << 16) * c2_; ay += __uint_as_float(u2 & 0xFFFF0000u) * c2_;
            ax += __uint_as_float(u3 << 16) * c3;  ay += __uint_as_float(u3 & 0xFFFF0000u) * c3;
            ax += __uint_as_float(u4 << 16) * c4;  ay += __uint_as_float(u4 & 0xFFFF0000u) * c4;
            ax += __uint_as_float(u5 << 16) * c5;  ay += __uint_as_float(u5 & 0xFFFF0000u) * c5;
            ax += __uint_as_float(u6 << 16) * c6;  ay += __uint_as_float(u6 & 0xFFFF0000u) * c6;
            ax += __uint_as_float(u7 << 16) * c7;  ay += __uint_as_float(u7 & 0xFFFF0000u) * c7;
        }
        for (; j < n; j += 2) {                   // tail; j+half==n reads cl=0: safe
            int   s = __shfl(sl, j + half);
            float c = __shfl(cl, j + half);
            unsigned u = hwu[(size_t)s * 32 + c2];
            ax += __uint_as_float(u << 16) * c;
            ay += __uint_as_float(u & 0xFFFF0000u) * c;
        }
    }

    // combine even/odd-edge halves (lanes l and l+32 hold partials of same cols)
    ax += __shfl_xor(ax, 32);
    ay += __shfl_xor(ay, 32);

    if (FUSE_LN) {
        float2 o = reinterpret_cast<const float2*>(ori)[(size_t)row * 32 + c2];
        float v0 = ax + o.x, v1 = ay + o.y;
        float s = v0 + v1;
        #pragma unroll
        for (int off = 16; off > 0; off >>= 1) s += __shfl_xor(s, off);
        float mu = s * (1.0f / 64.0f);
        float d0 = v0 - mu, d1 = v1 - mu;
        float q = d0 * d0 + d1 * d1;
        #pragma unroll
        for (int off = 16; off > 0; off >>= 1) q += __shfl_xor(q, off);
        float r = rsqrtf(q * (1.0f / 64.0f) + EPSV);
        float2 wv = reinterpret_cast<const float2*>(lnw)[c2];
        float2 bv = reinterpret_cast<const float2*>(lnb)[c2];
        if (half == 0) {
            float y0 = fmaxf(d0 * r * wv.x + bv.x, 0.0f);
            float y1 = fmaxf(d1 * r * wv.y + bv.y, 0.0f);
            reinterpret_cast<float2*>(out)[(size_t)row * 32 + c2] = make_float2(y0, y1);
        }
    } else {
        if (half == 0)
            reinterpret_cast<float2*>(out)[(size_t)row * 32 + c2] = make_float2(ax, ay);
    }
}

extern "C" void kernel_launch(void* const* d_in, const int* in_sizes, int n_in,
                              void* d_out, int out_size, void* d_ws, size_t ws_size,
                              hipStream_t stream)
{
    const float* in_feat = (const float*)d_in[0];
    const int*   ei      = (const int*)d_in[1];   // [2][E]
    const float* lin_w   = (const float*)d_in[2];
    const float* lin_b   = (const float*)d_in[3];
    const float* conv_w  = (const float*)d_in[4];
    const float* conv_b  = (const float*)d_in[5];
    const float* ln_w    = (const float*)d_in[6]; // [3][64]
    const float* ln_b    = (const float*)d_in[7];
    float* out = (float*)d_out;
    float* ws  = (float*)d_ws;

    // Workspace (~92 MB):
    float* dinv = ws;                          // NNP floats
    int*   cnt  = (int*)(ws + NNP);            // NNP
    int*   rowp = cnt + NNP;                   // NNP (rowp[NN] = NE)
    int*   bh   = rowp + NNP;                  // SCN
    int*   offs = bh + SCN;                    // SCN
    int*   bsum = offs + SCN;                  // 1024
    int*   bsumA= bsum + 1024;                 // 1024
    uint2* part = (uint2*)(bsumA + 1024);      // NE uint2 (8B-aligned)
    uint2* es2  = part + NE;                   // NE uint2 (exact CSR, (src,coef))
    float* h    = (float*)(es2 + NE);          // NN*HF fp32
    float* ori  = h + (size_t)NN * HF;         // NN*HF fp32
    unsigned short* hw16 = (unsigned short*)(ori + (size_t)NN * HF);  // NN*HF bf16
    unsigned* hwu = (unsigned*)hw16;           // same buffer, uint view

    // ---- CSR build pipeline (7 launches) ----
    k_zero<<<NNP / 256, 256, 0, stream>>>(cnt);
    k_hist2<<<PBLK, 256, 0, stream>>>(ei, cnt, bh);
    k_scanB1<<<GB + AB, 256, 0, stream>>>(bh, offs, cnt, rowp, dinv, bsum, bsumA);
    k_scanB2<<<1, 1024, 0, stream>>>(bsum, bsumA);
    k_scanB3<<<GB + AB, 256, 0, stream>>>(offs, rowp, bsum, bsumA);
    k_part<<<PBLK, 256, 0, stream>>>(ei, dinv, offs, part);
    k_fine<<<NBUK, 256, 0, stream>>>(part, rowp, es2);

    // ---- h = ori = in_feat @ lin_w + lin_b (fp32) ----
    k_gemm<128, true, true, false><<<(NN + 63) / 64, 256, 0, stream>>>(
        in_feat, lin_w, lin_b, h, ori);

    // ---- 3 propagation steps ----
    for (int it = 0; it < 3; ++it) {
        // hw16 = bf16(h @ conv_w)
        k_gemm<64, false, false, true><<<(NN + 63) / 64, 256, 0, stream>>>(
            h, conv_w, nullptr, hw16, nullptr);
        if (it < 2) {
            k_gather3<1><<<(NN + 3) / 4, 256, 0, stream>>>(
                rowp, es2, dinv, hwu, conv_b, ori,
                ln_w + (it + 1) * HF, ln_b + (it + 1) * HF, h);
        } else {
            k_gather3<0><<<(NN + 3) / 4, 256, 0, stream>>>(
                rowp, es2, dinv, hwu, conv_b, nullptr, nullptr, nullptr, out);
        }
    }
}

// Round 8
// 423.128 us; speedup vs baseline: 6.0162x; 1.1501x over previous
//
#include <hip/hip_runtime.h>

// GCN_56521769616159 R8: kill the global per-node histogram (R7's k_hist2 was
// 66us, WRITE=50MB: random 4B global atomics dirty whole 64B lines). In-degree
// is derived per bucket AFTER partitioning: one block per bucket LDS-histograms
// dstlow over its contiguous part span, in-block scans 256 counters -> rowp +
// dinv directly. part records shrink uint2->uint (s|dstlow, 25 bits); coef is
// computed in the fine pass (dinv[dst] from LDS, dinv[src] from L2).

static constexpr int NN    = 100000;
static constexpr int NE    = 1600000;
static constexpr int HF    = 64;
static constexpr int NNP   = 100352;        // NN padded to 256
static constexpr int NBUK  = 391;           // ceil(NN/256): bucket = dst>>8
static constexpr int PBLK  = 512;           // partition blocks
static constexpr int CHUNK = NE / PBLK;     // 3125 edges per partition block
static constexpr int SCN   = NBUK * PBLK;   // 200192 = 782*256
static constexpr int GB    = SCN / 256;     // 782 scan blocks
#define EPSV 1e-5f

static __device__ __forceinline__ unsigned short f2bf(float f) {
    unsigned u = __float_as_uint(f);
    u = (u + 0x7FFFu + ((u >> 16) & 1u)) >> 16;     // RNE
    return (unsigned short)u;
}

// Per-block bucket histogram (LDS atomics only; no global atomics).
__global__ __launch_bounds__(256) void k_bhist(const int* __restrict__ ei,
                                               int* __restrict__ bh) {
    __shared__ int cnts[NBUK];
    for (int b = threadIdx.x; b < NBUK; b += 256) cnts[b] = 0;
    __syncthreads();
    int base = blockIdx.x * CHUNK;
    for (int k = threadIdx.x; k < CHUNK; k += 256)
        atomicAdd(&cnts[ei[NE + base + k] >> 8], 1);
    __syncthreads();
    for (int b = threadIdx.x; b < NBUK; b += 256)
        bh[blockIdx.x * NBUK + b] = cnts[b];
}

// Exclusive scan of bh in bucket-major order -> offs[buk*PBLK + blk].
__global__ __launch_bounds__(256) void k_scan1g(const int* __restrict__ bh,
                                                int* __restrict__ offs,
                                                int* __restrict__ bsum) {
    __shared__ int sm[256];
    int i = blockIdx.x * 256 + threadIdx.x;      // i < SCN always
    int buk = i >> 9, blk = i & (PBLK - 1);
    int x = bh[blk * NBUK + buk];
    sm[threadIdx.x] = x;
    __syncthreads();
    int v = x;
    for (int off = 1; off < 256; off <<= 1) {
        int t = (threadIdx.x >= (unsigned)off) ? sm[threadIdx.x - off] : 0;
        __syncthreads();
        v += t;
        sm[threadIdx.x] = v;
        __syncthreads();
    }
    offs[i] = v - x;
    if (threadIdx.x == 255) bsum[blockIdx.x] = v;
}

__global__ __launch_bounds__(1024) void k_scan2g(int* __restrict__ bsum, int nb) {
    __shared__ int sm[1024];
    int t = threadIdx.x;
    int x = (t < nb) ? bsum[t] : 0;
    sm[t] = x;
    __syncthreads();
    int v = x;
    for (int off = 1; off < 1024; off <<= 1) {
        int tt = (t >= off) ? sm[t - off] : 0;
        __syncthreads();
        v += tt;
        sm[t] = v;
        __syncthreads();
    }
    if (t < nb) bsum[t] = v - x;
}

__global__ __launch_bounds__(256) void k_scan3g(int* __restrict__ offs,
                                                const int* __restrict__ bsum) {
    int i = blockIdx.x * 256 + threadIdx.x;
    offs[i] += bsum[blockIdx.x];
}

// Partition: scatter packed (src | dstlow<<17) uint into bucket-major order.
__global__ __launch_bounds__(256) void k_part(const int* __restrict__ ei,
                                              const int* __restrict__ offs,
                                              unsigned* __restrict__ part) {
    __shared__ int cur[NBUK];
    int blk = blockIdx.x;
    for (int b = threadIdx.x; b < NBUK; b += 256) cur[b] = offs[b * PBLK + blk];
    __syncthreads();
    int base = blk * CHUNK;
    for (int k = threadIdx.x; k < CHUNK; k += 256) {
        int s = ei[base + k];
        int d = ei[NE + base + k];
        int pos = atomicAdd(&cur[d >> 8], 1);
        part[pos] = (unsigned)s | ((unsigned)(d & 255) << 17);   // s < 2^17
    }
}

// Per-bucket: histogram dstlow over the bucket's contiguous part span, in-block
// exclusive scan -> rowp[row] = bstart + scan, dinv[row] = rsqrt(cnt+1).
// Replaces the global-atomic node histogram + node-scan pipeline entirely.
__global__ __launch_bounds__(256) void k_fineA(const unsigned* __restrict__ part,
                                               const int* __restrict__ offs,
                                               int* __restrict__ rowp,
                                               float* __restrict__ dinv) {
    __shared__ int cnt[256];
    __shared__ int sm[256];
    int b = blockIdx.x;
    int row0 = b << 8;
    cnt[threadIdx.x] = 0;
    __syncthreads();
    int bstart = offs[b * PBLK];
    int bend   = (b == NBUK - 1) ? NE : offs[(b + 1) * PBLK];
    for (int k = bstart + threadIdx.x; k < bend; k += 256)
        atomicAdd(&cnt[part[k] >> 17], 1);
    __syncthreads();
    int x = cnt[threadIdx.x];
    sm[threadIdx.x] = x;
    __syncthreads();
    int v = x;
    for (int off = 1; off < 256; off <<= 1) {
        int t = (threadIdx.x >= (unsigned)off) ? sm[threadIdx.x - off] : 0;
        __syncthreads();
        v += t;
        sm[threadIdx.x] = v;
        __syncthreads();
    }
    int row = row0 + threadIdx.x;
    if (row < NN) {
        rowp[row] = bstart + v - x;
        dinv[row] = rsqrtf((float)x + 1.0f);     // +1 self-loop
    }
    if (row == NN - 1 || (b == NBUK - 1 && threadIdx.x == 255))
        rowp[NN] = NE;
}

// Per-bucket counting sort -> exact CSR with coef: es2[pos] = (src, coef).
// dinv[dst] from LDS (bucket-local); dinv[src] random read (L2-resident 400KB).
__global__ __launch_bounds__(256) void k_fineB(const unsigned* __restrict__ part,
                                               const int* __restrict__ rowp,
                                               const int* __restrict__ offs,
                                               const float* __restrict__ dinv,
                                               uint2* __restrict__ es2) {
    __shared__ int   cur[256];
    __shared__ float dlo[256];
    int b = blockIdx.x;
    int row0 = b << 8;
    int row = row0 + threadIdx.x;
    if (row < NN) {
        cur[threadIdx.x] = rowp[row];
        dlo[threadIdx.x] = dinv[row];
    } else {
        cur[threadIdx.x] = 0;
        dlo[threadIdx.x] = 0.0f;
    }
    __syncthreads();
    int bstart = offs[b * PBLK];
    int bend   = (b == NBUK - 1) ? NE : offs[(b + 1) * PBLK];
    for (int k = bstart + threadIdx.x; k < bend; k += 256) {
        unsigned p = part[k];
        int s  = (int)(p & 0x1FFFF);
        int dl = (int)(p >> 17);
        float c = dinv[s] * dlo[dl];
        int pos = atomicAdd(&cur[dl], 1);
        es2[pos] = make_uint2(p & 0x1FFFF, __float_as_uint(c));
    }
}

// Tiled fp32 GEMM: out[N,64] = A[N,K] @ W[K,64] (+bias). 64x64 tile, 256 thr,
// 4x4 outputs/thread. DUAL writes two fp32 copies; OUTBF writes bf16 (ushort).
template<int K, bool DUAL, bool BIAS, bool OUTBF>
__global__ __launch_bounds__(256) void k_gemm(const float* __restrict__ A,
                                              const float* __restrict__ W,
                                              const float* __restrict__ bias,
                                              void* __restrict__ out0v,
                                              float* __restrict__ out1)
{
    __shared__ float As[64][65];
    __shared__ float Ws[64][64];
    const int tid = threadIdx.x;
    const int tx = tid & 15, ty = tid >> 4;
    const int c0 = tx * 4, r0 = ty * 4;
    const int row0 = blockIdx.x * 64;
    float acc[4][4] = {};

    for (int kt = 0; kt < K / 64; ++kt) {
        #pragma unroll
        for (int q = 0; q < 4; ++q) {
            int vid = q * 256 + tid;
            int row = vid >> 4;
            int kq  = vid & 15;
            if (row0 + row < NN) {
                float4 v = *reinterpret_cast<const float4*>(
                    &A[(size_t)(row0 + row) * K + kt * 64 + kq * 4]);
                As[row][kq * 4 + 0] = v.x; As[row][kq * 4 + 1] = v.y;
                As[row][kq * 4 + 2] = v.z; As[row][kq * 4 + 3] = v.w;
            }
            *reinterpret_cast<float4*>(&Ws[row][kq * 4]) =
                *reinterpret_cast<const float4*>(&W[(size_t)(kt * 64 + row) * HF + kq * 4]);
        }
        __syncthreads();
        #pragma unroll 8
        for (int k = 0; k < 64; ++k) {
            float4 wv = *reinterpret_cast<const float4*>(&Ws[k][c0]);
            float a0 = As[r0 + 0][k], a1 = As[r0 + 1][k];
            float a2 = As[r0 + 2][k], a3 = As[r0 + 3][k];
            acc[0][0] += a0 * wv.x; acc[0][1] += a0 * wv.y; acc[0][2] += a0 * wv.z; acc[0][3] += a0 * wv.w;
            acc[1][0] += a1 * wv.x; acc[1][1] += a1 * wv.y; acc[1][2] += a1 * wv.z; acc[1][3] += a1 * wv.w;
            acc[2][0] += a2 * wv.x; acc[2][1] += a2 * wv.y; acc[2][2] += a2 * wv.z; acc[2][3] += a2 * wv.w;
            acc[3][0] += a3 * wv.x; acc[3][1] += a3 * wv.y; acc[3][2] += a3 * wv.z; acc[3][3] += a3 * wv.w;
        }
        __syncthreads();
    }

    float4 bv = make_float4(0.f, 0.f, 0.f, 0.f);
    if (BIAS) bv = *reinterpret_cast<const float4*>(&bias[c0]);
    #pragma unroll
    for (int i = 0; i < 4; ++i) {
        int r = row0 + r0 + i;
        if (r < NN) {
            float4 o = make_float4(acc[i][0] + bv.x, acc[i][1] + bv.y,
                                   acc[i][2] + bv.z, acc[i][3] + bv.w);
            if (OUTBF) {
                ushort4 ob;
                ob.x = f2bf(o.x); ob.y = f2bf(o.y);
                ob.z = f2bf(o.z); ob.w = f2bf(o.w);
                *reinterpret_cast<ushort4*>(
                    &((unsigned short*)out0v)[(size_t)r * HF + c0]) = ob;
            } else {
                *reinterpret_cast<float4*>(&((float*)out0v)[(size_t)r * HF + c0]) = o;
                if (DUAL)
                    *reinterpret_cast<float4*>(&out1[(size_t)r * HF + c0]) = o;
            }
        }
    }
}

// W=2 gather: wave per dst row. hw16 viewed as uint[NN][32] (2xbf16 per uint).
// Lane l: half = l>>5 (even/odd edge), c2 = l&31 (column pair).
template<int FUSE_LN>
__global__ __launch_bounds__(256) void k_gather3(const int* __restrict__ rowp,
                                                 const uint2* __restrict__ es2,
                                                 const float* __restrict__ dinv,
                                                 const unsigned* __restrict__ hwu,
                                                 const float* __restrict__ cb,
                                                 const float* __restrict__ ori,
                                                 const float* __restrict__ lnw,
                                                 const float* __restrict__ lnb,
                                                 float* __restrict__ out)
{
    int row = blockIdx.x * 4 + (threadIdx.x >> 6);
    if (row >= NN) return;                       // wave-uniform
    const int lane = threadIdx.x & 63;
    const int half = lane >> 5;
    const int c2   = lane & 31;
    const float dd = dinv[row];

    float ax, ay;
    if (half == 0) {                             // self-loop + bias in half 0 only
        unsigned u = hwu[(size_t)row * 32 + c2];
        float2 cbv = reinterpret_cast<const float2*>(cb)[c2];
        float s2 = dd * dd;
        ax = fmaf(__uint_as_float(u << 16),        s2, cbv.x);
        ay = fmaf(__uint_as_float(u & 0xFFFF0000u), s2, cbv.y);
    } else {
        ax = 0.0f; ay = 0.0f;
    }

    const int start = rowp[row], end = rowp[row + 1];
    for (int base = start; base < end; base += 64) {
        int n = end - base;
        if (n > 64) n = 64;
        int   sl = 0;
        float cl = 0.0f;                          // coef=0 for invalid lanes: safe
        if (lane < n) {
            uint2 p = es2[base + lane];
            sl = (int)p.x;
            cl = __uint_as_float(p.y);
        }
        int j = 0;
        for (; j + 16 <= n; j += 16) {            // 16 edges: 8 loads in flight
            int   s0 = __shfl(sl, j +  0 + half), s1 = __shfl(sl, j +  2 + half);
            int   s2_ = __shfl(sl, j +  4 + half), s3 = __shfl(sl, j +  6 + half);
            int   s4 = __shfl(sl, j +  8 + half), s5 = __shfl(sl, j + 10 + half);
            int   s6 = __shfl(sl, j + 12 + half), s7 = __shfl(sl, j + 14 + half);
            float c0 = __shfl(cl, j +  0 + half), c1 = __shfl(cl, j +  2 + half);
            float c2_ = __shfl(cl, j +  4 + half), c3 = __shfl(cl, j +  6 + half);
            float c4 = __shfl(cl, j +  8 + half), c5 = __shfl(cl, j + 10 + half);
            float c6 = __shfl(cl, j + 12 + half), c7 = __shfl(cl, j + 14 + half);
            unsigned u0 = hwu[(size_t)s0 * 32 + c2];
            unsigned u1 = hwu[(size_t)s1 * 32 + c2];
            unsigned u2 = hwu[(size_t)s2_ * 32 + c2];
            unsigned u3 = hwu[(size_t)s3 * 32 + c2];
            unsigned u4 = hwu[(size_t)s4 * 32 + c2];
            unsigned u5 = hwu[(size_t)s5 * 32 + c2];
            unsigned u6 = hwu[(size_t)s6 * 32 + c2];
            unsigned u7 = hwu[(size_t)s7 * 32 + c2];
            ax += __uint_as_float(u0 << 16) * c0;  ay += __uint_as_float(u0 & 0xFFFF0000u) * c0;
            ax += __uint_as_float(u1 << 16) * c1;  ay += __uint_as_float(u1 & 0xFFFF0000u) * c1;
            ax += __uint_as_float(u2 << 16) * c2_; ay += __uint_as_float(u2 & 0xFFFF0000u) * c2_;
            ax += __uint_as_float(u3 << 16) * c3;  ay += __uint_as_float(u3 & 0xFFFF0000u) * c3;
            ax += __uint_as_float(u4 << 16) * c4;  ay += __uint_as_float(u4 & 0xFFFF0000u) * c4;
            ax += __uint_as_float(u5 << 16) * c5;  ay += __uint_as_float(u5 & 0xFFFF0000u) * c5;
            ax += __uint_as_float(u6 << 16) * c6;  ay += __uint_as_float(u6 & 0xFFFF0000u) * c6;
            ax += __uint_as_float(u7 << 16) * c7;  ay += __uint_as_float(u7 & 0xFFFF0000u) * c7;
        }
        for (; j < n; j += 2) {                   // tail; j+half==n reads cl=0: safe
            int   s = __shfl(sl, j + half);
            float c = __shfl(cl, j + half);
            unsigned u = hwu[(size_t)s * 32 + c2];
            ax += __uint_as_float(u << 16) * c;
            ay += __uint_as_float(u & 0xFFFF0000u) * c;
        }
    }

    // combine even/odd-edge halves (lanes l and l+32 hold partials of same cols)
    ax += __shfl_xor(ax, 32);
    ay += __shfl_xor(ay, 32);

    if (FUSE_LN) {
        float2 o = reinterpret_cast<const float2*>(ori)[(size_t)row * 32 + c2];
        float v0 = ax + o.x, v1 = ay + o.y;
        float s = v0 + v1;
        #pragma unroll
        for (int off = 16; off > 0; off >>= 1) s += __shfl_xor(s, off);
        float mu = s * (1.0f / 64.0f);
        float d0 = v0 - mu, d1 = v1 - mu;
        float q = d0 * d0 + d1 * d1;
        #pragma unroll
        for (int off = 16; off > 0; off >>= 1) q += __shfl_xor(q, off);
        float r = rsqrtf(q * (1.0f / 64.0f) + EPSV);
        float2 wv = reinterpret_cast<const float2*>(lnw)[c2];
        float2 bv = reinterpret_cast<const float2*>(lnb)[c2];
        if (half == 0) {
            float y0 = fmaxf(d0 * r * wv.x + bv.x, 0.0f);
            float y1 = fmaxf(d1 * r * wv.y + bv.y, 0.0f);
            reinterpret_cast<float2*>(out)[(size_t)row * 32 + c2] = make_float2(y0, y1);
        }
    } else {
        if (half == 0)
            reinterpret_cast<float2*>(out)[(size_t)row * 32 + c2] = make_float2(ax, ay);
    }
}

extern "C" void kernel_launch(void* const* d_in, const int* in_sizes, int n_in,
                              void* d_out, int out_size, void* d_ws, size_t ws_size,
                              hipStream_t stream)
{
    const float* in_feat = (const float*)d_in[0];
    const int*   ei      = (const int*)d_in[1];   // [2][E]
    const float* lin_w   = (const float*)d_in[2];
    const float* lin_b   = (const float*)d_in[3];
    const float* conv_w  = (const float*)d_in[4];
    const float* conv_b  = (const float*)d_in[5];
    const float* ln_w    = (const float*)d_in[6]; // [3][64]
    const float* ln_b    = (const float*)d_in[7];
    float* out = (float*)d_out;
    float* ws  = (float*)d_ws;

    // Workspace (~86 MB):
    float*    dinv = ws;                         // NNP floats
    int*      rowp = (int*)(ws + NNP);           // NNP (rowp[NN] = NE)
    int*      bh   = rowp + NNP;                 // SCN
    int*      offs = bh + SCN;                   // SCN
    int*      bsum = offs + SCN;                 // 1024
    unsigned* part = (unsigned*)(bsum + 1024);   // NE uint (packed s|dstlow)
    uint2*    es2  = (uint2*)(part + NE);        // NE uint2 (exact CSR (src,coef))
    float*    h    = (float*)(es2 + NE);         // NN*HF fp32
    float*    ori  = h + (size_t)NN * HF;        // NN*HF fp32
    unsigned short* hw16 = (unsigned short*)(ori + (size_t)NN * HF);  // NN*HF bf16
    unsigned* hwu  = (unsigned*)hw16;            // same buffer, uint view

    // ---- CSR build pipeline (7 launches, zero global atomics) ----
    k_bhist<<<PBLK, 256, 0, stream>>>(ei, bh);
    k_scan1g<<<GB, 256, 0, stream>>>(bh, offs, bsum);
    k_scan2g<<<1, 1024, 0, stream>>>(bsum, GB);
    k_scan3g<<<GB, 256, 0, stream>>>(offs, bsum);
    k_part<<<PBLK, 256, 0, stream>>>(ei, offs, part);
    k_fineA<<<NBUK, 256, 0, stream>>>(part, offs, rowp, dinv);
    k_fineB<<<NBUK, 256, 0, stream>>>(part, rowp, offs, dinv, es2);

    // ---- h = ori = in_feat @ lin_w + lin_b (fp32) ----
    k_gemm<128, true, true, false><<<(NN + 63) / 64, 256, 0, stream>>>(
        in_feat, lin_w, lin_b, h, ori);

    // ---- 3 propagation steps ----
    for (int it = 0; it < 3; ++it) {
        // hw16 = bf16(h @ conv_w)
        k_gemm<64, false, false, true><<<(NN + 63) / 64, 256, 0, stream>>>(
            h, conv_w, nullptr, hw16, nullptr);
        if (it < 2) {
            k_gather3<1><<<(NN + 3) / 4, 256, 0, stream>>>(
                rowp, es2, dinv, hwu, conv_b, ori,
                ln_w + (it + 1) * HF, ln_b + (it + 1) * HF, h);
        } else {
            k_gather3<0><<<(NN + 3) / 4, 256, 0, stream>>>(
                rowp, es2, dinv, hwu, conv_b, nullptr, nullptr, nullptr, out);
        }
    }
}

// Round 9
// 360.630 us; speedup vs baseline: 7.0589x; 1.1733x over previous
//
#include <hip/hip_runtime.h>

// GCN_56521769616159 R9: gather is latency/MLP-bound (R5->R8: halving bytes
// gave -8%, halving instructions gave 0%; VALUBusy 42%, 2TB/s). Fix: half-wave
// per row (lanes 0-31 row A, 32-63 row B) -> 2x outstanding loads/wave, and a
// deg-16 row fits one 32-edge batch. Plus bf16 h/ori (halves epilogue traffic)
// and scan3g folded into consumers (13 launches).

static constexpr int NN    = 100000;
static constexpr int NE    = 1600000;
static constexpr int HF    = 64;
static constexpr int NNP   = 100352;        // NN padded to 256
static constexpr int NBUK  = 391;           // ceil(NN/256): bucket = dst>>8
static constexpr int PBLK  = 512;           // partition blocks
static constexpr int CHUNK = NE / PBLK;     // 3125 edges per partition block
static constexpr int SCN   = NBUK * PBLK;   // 200192 = 782*256
static constexpr int GB    = SCN / 256;     // 782 scan blocks
#define EPSV 1e-5f

static __device__ __forceinline__ unsigned short f2bf(float f) {
    unsigned u = __float_as_uint(f);
    u = (u + 0x7FFFu + ((u >> 16) & 1u)) >> 16;     // RNE
    return (unsigned short)u;
}
static __device__ __forceinline__ float bf_lo(unsigned u) {
    return __uint_as_float(u << 16);
}
static __device__ __forceinline__ float bf_hi(unsigned u) {
    return __uint_as_float(u & 0xFFFF0000u);
}

// Per-block bucket histogram (LDS atomics only).
__global__ __launch_bounds__(256) void k_bhist(const int* __restrict__ ei,
                                               int* __restrict__ bh) {
    __shared__ int cnts[NBUK];
    for (int b = threadIdx.x; b < NBUK; b += 256) cnts[b] = 0;
    __syncthreads();
    int base = blockIdx.x * CHUNK;
    for (int k = threadIdx.x; k < CHUNK; k += 256)
        atomicAdd(&cnts[ei[NE + base + k] >> 8], 1);
    __syncthreads();
    for (int b = threadIdx.x; b < NBUK; b += 256)
        bh[blockIdx.x * NBUK + b] = cnts[b];
}

// Exclusive scan of bh in bucket-major order -> offs[buk*PBLK + blk] (within
// scan-block); bsum gets per-scan-block totals. Consumers add bsum[i>>8].
__global__ __launch_bounds__(256) void k_scan1g(const int* __restrict__ bh,
                                                int* __restrict__ offs,
                                                int* __restrict__ bsum) {
    __shared__ int sm[256];
    int i = blockIdx.x * 256 + threadIdx.x;      // i < SCN always
    int buk = i >> 9, blk = i & (PBLK - 1);
    int x = bh[blk * NBUK + buk];
    sm[threadIdx.x] = x;
    __syncthreads();
    int v = x;
    for (int off = 1; off < 256; off <<= 1) {
        int t = (threadIdx.x >= (unsigned)off) ? sm[threadIdx.x - off] : 0;
        __syncthreads();
        v += t;
        sm[threadIdx.x] = v;
        __syncthreads();
    }
    offs[i] = v - x;
    if (threadIdx.x == 255) bsum[blockIdx.x] = v;
}

__global__ __launch_bounds__(1024) void k_scan2g(int* __restrict__ bsum, int nb) {
    __shared__ int sm[1024];
    int t = threadIdx.x;
    int x = (t < nb) ? bsum[t] : 0;
    sm[t] = x;
    __syncthreads();
    int v = x;
    for (int off = 1; off < 1024; off <<= 1) {
        int tt = (t >= off) ? sm[t - off] : 0;
        __syncthreads();
        v += tt;
        sm[t] = v;
        __syncthreads();
    }
    if (t < nb) bsum[t] = v - x;
}

// Partition: scatter packed (src | dstlow<<17) into bucket-major order.
// Cursor init folds the bsum add (scan3g removed).
__global__ __launch_bounds__(256) void k_part(const int* __restrict__ ei,
                                              const int* __restrict__ offs,
                                              const int* __restrict__ bsum,
                                              unsigned* __restrict__ part) {
    __shared__ int cur[NBUK];
    int blk = blockIdx.x;
    for (int b = threadIdx.x; b < NBUK; b += 256) {
        int i = b * PBLK + blk;
        cur[b] = offs[i] + bsum[i >> 8];
    }
    __syncthreads();
    int base = blk * CHUNK;
    for (int k = threadIdx.x; k < CHUNK; k += 256) {
        int s = ei[base + k];
        int d = ei[NE + base + k];
        int pos = atomicAdd(&cur[d >> 8], 1);
        part[pos] = (unsigned)s | ((unsigned)(d & 255) << 17);   // s < 2^17
    }
}

// Per-bucket: histogram dstlow over the bucket's part span, in-block scan ->
// rowp[row], dinv[row].
__global__ __launch_bounds__(256) void k_fineA(const unsigned* __restrict__ part,
                                               const int* __restrict__ offs,
                                               const int* __restrict__ bsum,
                                               int* __restrict__ rowp,
                                               float* __restrict__ dinv) {
    __shared__ int cnt[256];
    __shared__ int sm[256];
    int b = blockIdx.x;
    int row0 = b << 8;
    cnt[threadIdx.x] = 0;
    __syncthreads();
    int i0 = b * PBLK;
    int bstart = offs[i0] + bsum[i0 >> 8];
    int bend;
    if (b == NBUK - 1) bend = NE;
    else { int i1 = (b + 1) * PBLK; bend = offs[i1] + bsum[i1 >> 8]; }
    for (int k = bstart + threadIdx.x; k < bend; k += 256)
        atomicAdd(&cnt[part[k] >> 17], 1);
    __syncthreads();
    int x = cnt[threadIdx.x];
    sm[threadIdx.x] = x;
    __syncthreads();
    int v = x;
    for (int off = 1; off < 256; off <<= 1) {
        int t = (threadIdx.x >= (unsigned)off) ? sm[threadIdx.x - off] : 0;
        __syncthreads();
        v += t;
        sm[threadIdx.x] = v;
        __syncthreads();
    }
    int row = row0 + threadIdx.x;
    if (row < NN) {
        rowp[row] = bstart + v - x;
        dinv[row] = rsqrtf((float)x + 1.0f);     // +1 self-loop
    }
    if (row == NN - 1) rowp[NN] = NE;
}

// Per-bucket counting sort -> exact CSR (src, coef).
__global__ __launch_bounds__(256) void k_fineB(const unsigned* __restrict__ part,
                                               const int* __restrict__ rowp,
                                               const int* __restrict__ offs,
                                               const int* __restrict__ bsum,
                                               const float* __restrict__ dinv,
                                               uint2* __restrict__ es2) {
    __shared__ int   cur[256];
    __shared__ float dlo[256];
    int b = blockIdx.x;
    int row0 = b << 8;
    int row = row0 + threadIdx.x;
    if (row < NN) {
        cur[threadIdx.x] = rowp[row];
        dlo[threadIdx.x] = dinv[row];
    } else {
        cur[threadIdx.x] = 0;
        dlo[threadIdx.x] = 0.0f;
    }
    __syncthreads();
    int i0 = b * PBLK;
    int bstart = offs[i0] + bsum[i0 >> 8];
    int bend;
    if (b == NBUK - 1) bend = NE;
    else { int i1 = (b + 1) * PBLK; bend = offs[i1] + bsum[i1 >> 8]; }
    for (int k = bstart + threadIdx.x; k < bend; k += 256) {
        unsigned p = part[k];
        int s  = (int)(p & 0x1FFFF);
        int dl = (int)(p >> 17);
        float c = dinv[s] * dlo[dl];
        int pos = atomicAdd(&cur[dl], 1);
        es2[pos] = make_uint2((unsigned)s, __float_as_uint(c));
    }
}

// GEMM1: h16 = ori16 = bf16(in_feat[N,128] @ lin_w + lin_b). fp32 math.
__global__ __launch_bounds__(256) void k_gemmA(const float* __restrict__ A,
                                               const float* __restrict__ W,
                                               const float* __restrict__ bias,
                                               unsigned short* __restrict__ h16,
                                               unsigned short* __restrict__ ori16)
{
    __shared__ float As[64][65];
    __shared__ float Ws[64][64];
    const int tid = threadIdx.x;
    const int tx = tid & 15, ty = tid >> 4;
    const int c0 = tx * 4, r0 = ty * 4;
    const int row0 = blockIdx.x * 64;
    float acc[4][4] = {};

    for (int kt = 0; kt < 2; ++kt) {
        #pragma unroll
        for (int q = 0; q < 4; ++q) {
            int vid = q * 256 + tid;
            int row = vid >> 4;
            int kq  = vid & 15;
            if (row0 + row < NN) {
                float4 v = *reinterpret_cast<const float4*>(
                    &A[(size_t)(row0 + row) * 128 + kt * 64 + kq * 4]);
                As[row][kq * 4 + 0] = v.x; As[row][kq * 4 + 1] = v.y;
                As[row][kq * 4 + 2] = v.z; As[row][kq * 4 + 3] = v.w;
            }
            *reinterpret_cast<float4*>(&Ws[row][kq * 4]) =
                *reinterpret_cast<const float4*>(&W[(size_t)(kt * 64 + row) * HF + kq * 4]);
        }
        __syncthreads();
        #pragma unroll 8
        for (int k = 0; k < 64; ++k) {
            float4 wv = *reinterpret_cast<const float4*>(&Ws[k][c0]);
            float a0 = As[r0 + 0][k], a1 = As[r0 + 1][k];
            float a2 = As[r0 + 2][k], a3 = As[r0 + 3][k];
            acc[0][0] += a0 * wv.x; acc[0][1] += a0 * wv.y; acc[0][2] += a0 * wv.z; acc[0][3] += a0 * wv.w;
            acc[1][0] += a1 * wv.x; acc[1][1] += a1 * wv.y; acc[1][2] += a1 * wv.z; acc[1][3] += a1 * wv.w;
            acc[2][0] += a2 * wv.x; acc[2][1] += a2 * wv.y; acc[2][2] += a2 * wv.z; acc[2][3] += a2 * wv.w;
            acc[3][0] += a3 * wv.x; acc[3][1] += a3 * wv.y; acc[3][2] += a3 * wv.z; acc[3][3] += a3 * wv.w;
        }
        __syncthreads();
    }

    float4 bv = *reinterpret_cast<const float4*>(&bias[c0]);
    #pragma unroll
    for (int i = 0; i < 4; ++i) {
        int r = row0 + r0 + i;
        if (r < NN) {
            ushort4 ob;
            ob.x = f2bf(acc[i][0] + bv.x); ob.y = f2bf(acc[i][1] + bv.y);
            ob.z = f2bf(acc[i][2] + bv.z); ob.w = f2bf(acc[i][3] + bv.w);
            *reinterpret_cast<ushort4*>(&h16[(size_t)r * HF + c0])   = ob;
            *reinterpret_cast<ushort4*>(&ori16[(size_t)r * HF + c0]) = ob;
        }
    }
}

// GEMM2: hw16 = bf16(h16[N,64] @ conv_w). A staged from bf16, fp32 math.
__global__ __launch_bounds__(256) void k_gemmB(const unsigned* __restrict__ h16u,
                                               const float* __restrict__ W,
                                               unsigned short* __restrict__ hw16)
{
    __shared__ float As[64][65];
    __shared__ float Ws[64][64];
    const int tid = threadIdx.x;
    const int tx = tid & 15, ty = tid >> 4;
    const int c0 = tx * 4, r0 = ty * 4;
    const int row0 = blockIdx.x * 64;
    float acc[4][4] = {};

    #pragma unroll
    for (int q = 0; q < 4; ++q) {
        int vid = q * 256 + tid;
        int row = vid >> 4;
        int kq  = vid & 15;
        if (row0 + row < NN) {
            uint2 v = *reinterpret_cast<const uint2*>(
                &h16u[(size_t)(row0 + row) * 32 + kq * 2]);
            As[row][kq * 4 + 0] = bf_lo(v.x); As[row][kq * 4 + 1] = bf_hi(v.x);
            As[row][kq * 4 + 2] = bf_lo(v.y); As[row][kq * 4 + 3] = bf_hi(v.y);
        }
        *reinterpret_cast<float4*>(&Ws[row][kq * 4]) =
            *reinterpret_cast<const float4*>(&W[(size_t)row * HF + kq * 4]);
    }
    __syncthreads();
    #pragma unroll 8
    for (int k = 0; k < 64; ++k) {
        float4 wv = *reinterpret_cast<const float4*>(&Ws[k][c0]);
        float a0 = As[r0 + 0][k], a1 = As[r0 + 1][k];
        float a2 = As[r0 + 2][k], a3 = As[r0 + 3][k];
        acc[0][0] += a0 * wv.x; acc[0][1] += a0 * wv.y; acc[0][2] += a0 * wv.z; acc[0][3] += a0 * wv.w;
        acc[1][0] += a1 * wv.x; acc[1][1] += a1 * wv.y; acc[1][2] += a1 * wv.z; acc[1][3] += a1 * wv.w;
        acc[2][0] += a2 * wv.x; acc[2][1] += a2 * wv.y; acc[2][2] += a2 * wv.z; acc[2][3] += a2 * wv.w;
        acc[3][0] += a3 * wv.x; acc[3][1] += a3 * wv.y; acc[3][2] += a3 * wv.z; acc[3][3] += a3 * wv.w;
    }

    #pragma unroll
    for (int i = 0; i < 4; ++i) {
        int r = row0 + r0 + i;
        if (r < NN) {
            ushort4 ob;
            ob.x = f2bf(acc[i][0]); ob.y = f2bf(acc[i][1]);
            ob.z = f2bf(acc[i][2]); ob.w = f2bf(acc[i][3]);
            *reinterpret_cast<ushort4*>(&hw16[(size_t)r * HF + c0]) = ob;
        }
    }
}

// Half-wave-per-row gather: lanes 0-31 row A, 32-63 row B (adjacent CSR rows).
// Each lane owns column pair c2 (uint = 2 bf16). 32-edge batches, 8-deep
// unrolled row loads -> 16 outstanding loads/wave. All shuffles width-32.
template<int FUSE_LN>
__global__ __launch_bounds__(256) void k_gather4(const int* __restrict__ rowp,
                                                 const uint2* __restrict__ es2,
                                                 const float* __restrict__ dinv,
                                                 const unsigned* __restrict__ hwu,
                                                 const float* __restrict__ cb,
                                                 const unsigned* __restrict__ ori16,
                                                 const float* __restrict__ lnw,
                                                 const float* __restrict__ lnb,
                                                 void* __restrict__ outv)
{
    int row = blockIdx.x * 8 + (threadIdx.x >> 5);
    if (row >= NN) return;                       // uniform per half-wave
    const int c2 = threadIdx.x & 31;
    const float dd = dinv[row];

    unsigned su = hwu[(size_t)row * 32 + c2];    // self-loop row
    float2 cbv = reinterpret_cast<const float2*>(cb)[c2];
    float s2 = dd * dd;
    float ax = fmaf(bf_lo(su), s2, cbv.x);
    float ay = fmaf(bf_hi(su), s2, cbv.y);

    const int start = rowp[row], end = rowp[row + 1];
    for (int base = start; base < end; base += 32) {
        int n = end - base;
        if (n > 32) n = 32;
        int   sl = 0;
        float cl = 0.0f;
        if (c2 < n) {
            uint2 p = es2[base + c2];
            sl = (int)p.x;
            cl = __uint_as_float(p.y);
        }
        int j = 0;
        for (; j + 8 <= n; j += 8) {
            unsigned uu[8]; float cc[8];
            #pragma unroll
            for (int q = 0; q < 8; ++q) {
                int s = __shfl(sl, j + q, 32);
                cc[q] = __shfl(cl, j + q, 32);
                uu[q] = hwu[(size_t)s * 32 + c2];
            }
            #pragma unroll
            for (int q = 0; q < 8; ++q) {
                ax += bf_lo(uu[q]) * cc[q];
                ay += bf_hi(uu[q]) * cc[q];
            }
        }
        for (; j < n; ++j) {
            int   s = __shfl(sl, j, 32);
            float c = __shfl(cl, j, 32);
            unsigned u = hwu[(size_t)s * 32 + c2];
            ax += bf_lo(u) * c;
            ay += bf_hi(u) * c;
        }
    }

    if (FUSE_LN) {
        unsigned uo = ori16[(size_t)row * 32 + c2];
        float v0 = ax + bf_lo(uo), v1 = ay + bf_hi(uo);
        float s = v0 + v1;
        #pragma unroll
        for (int off = 16; off > 0; off >>= 1) s += __shfl_xor(s, off, 32);
        float mu = s * (1.0f / 64.0f);
        float d0 = v0 - mu, d1 = v1 - mu;
        float q2 = d0 * d0 + d1 * d1;
        #pragma unroll
        for (int off = 16; off > 0; off >>= 1) q2 += __shfl_xor(q2, off, 32);
        float r = rsqrtf(q2 * (1.0f / 64.0f) + EPSV);
        float2 wv = reinterpret_cast<const float2*>(lnw)[c2];
        float2 bv = reinterpret_cast<const float2*>(lnb)[c2];
        float y0 = fmaxf(fmaf(d0 * r, wv.x, bv.x), 0.0f);
        float y1 = fmaxf(fmaf(d1 * r, wv.y, bv.y), 0.0f);
        ((unsigned*)outv)[(size_t)row * 32 + c2] =
            (unsigned)f2bf(y0) | ((unsigned)f2bf(y1) << 16);
    } else {
        reinterpret_cast<float2*>(outv)[(size_t)row * 32 + c2] = make_float2(ax, ay);
    }
}

extern "C" void kernel_launch(void* const* d_in, const int* in_sizes, int n_in,
                              void* d_out, int out_size, void* d_ws, size_t ws_size,
                              hipStream_t stream)
{
    const float* in_feat = (const float*)d_in[0];
    const int*   ei      = (const int*)d_in[1];   // [2][E]
    const float* lin_w   = (const float*)d_in[2];
    const float* lin_b   = (const float*)d_in[3];
    const float* conv_w  = (const float*)d_in[4];
    const float* conv_b  = (const float*)d_in[5];
    const float* ln_w    = (const float*)d_in[6]; // [3][64]
    const float* ln_b    = (const float*)d_in[7];
    float* out = (float*)d_out;
    float* ws  = (float*)d_ws;

    // Workspace (~62 MB):
    float*    dinv = ws;                         // NNP floats
    int*      rowp = (int*)(ws + NNP);           // NNP (rowp[NN] = NE)
    int*      bh   = rowp + NNP;                 // SCN
    int*      offs = bh + SCN;                   // SCN
    int*      bsum = offs + SCN;                 // 1024
    unsigned* part = (unsigned*)(bsum + 1024);   // NE uint (packed s|dstlow)
    uint2*    es2  = (uint2*)(part + NE);        // NE uint2 (exact CSR (src,coef))
    unsigned short* h16  = (unsigned short*)(es2 + NE);       // NN*HF bf16
    unsigned short* ori16 = h16 + (size_t)NN * HF;            // NN*HF bf16
    unsigned short* hw16  = ori16 + (size_t)NN * HF;          // NN*HF bf16
    unsigned* h16u  = (unsigned*)h16;
    unsigned* ori16u = (unsigned*)ori16;
    unsigned* hwu   = (unsigned*)hw16;

    // ---- CSR build (6 launches, zero global atomics) ----
    k_bhist<<<PBLK, 256, 0, stream>>>(ei, bh);
    k_scan1g<<<GB, 256, 0, stream>>>(bh, offs, bsum);
    k_scan2g<<<1, 1024, 0, stream>>>(bsum, GB);
    k_part<<<PBLK, 256, 0, stream>>>(ei, offs, bsum, part);
    k_fineA<<<NBUK, 256, 0, stream>>>(part, offs, bsum, rowp, dinv);
    k_fineB<<<NBUK, 256, 0, stream>>>(part, rowp, offs, bsum, dinv, es2);

    // ---- h16 = ori16 = bf16(in_feat @ lin_w + lin_b) ----
    k_gemmA<<<(NN + 63) / 64, 256, 0, stream>>>(in_feat, lin_w, lin_b, h16, ori16);

    // ---- 3 propagation steps ----
    for (int it = 0; it < 3; ++it) {
        k_gemmB<<<(NN + 63) / 64, 256, 0, stream>>>(h16u, conv_w, hw16);
        if (it < 2) {
            k_gather4<1><<<(NN + 7) / 8, 256, 0, stream>>>(
                rowp, es2, dinv, hwu, conv_b, ori16u,
                ln_w + (it + 1) * HF, ln_b + (it + 1) * HF, h16u);
        } else {
            k_gather4<0><<<(NN + 7) / 8, 256, 0, stream>>>(
                rowp, es2, dinv, hwu, conv_b, nullptr, nullptr, nullptr, out);
        }
    }
}

// Round 10
// 344.907 us; speedup vs baseline: 7.3806x; 1.0456x over previous
//
#include <hip/hip_runtime.h>

// GCN_56521769616159 R10: GEMM rebuild. R9 counters: k_gemmA 44us (roofline
// ~12us) with VALUBusy 27%, 400K LDS bank conflicts, occupancy 28% --
// execution-bound on scalar LDS reads + VGPR-roundtrip staging. Fix:
// global_load_lds width-16 staging (linear LDS) + XOR-swizzled global source
// (chunk ^= (row>>2)&3) for conflict-free float4/uint4 inner-loop reads;
// W staged once; gemmB stages A as bf16 (exact; input already bf16).
// Gathers/CSR unchanged from R9.

static constexpr int NN    = 100000;
static constexpr int NE    = 1600000;
static constexpr int HF    = 64;
static constexpr int NNP   = 100352;        // NN padded to 256
static constexpr int NBUK  = 391;           // ceil(NN/256): bucket = dst>>8
static constexpr int PBLK  = 512;           // partition blocks
static constexpr int CHUNK = NE / PBLK;     // 3125 edges per partition block
static constexpr int SCN   = NBUK * PBLK;   // 200192 = 782*256
static constexpr int GB    = SCN / 256;     // 782 scan blocks
#define EPSV 1e-5f

#define GLD16(gp, lp) __builtin_amdgcn_global_load_lds( \
    (const __attribute__((address_space(1))) void*)(gp), \
    (__attribute__((address_space(3))) void*)(lp), 16, 0, 0)

static __device__ __forceinline__ unsigned short f2bf(float f) {
    unsigned u = __float_as_uint(f);
    u = (u + 0x7FFFu + ((u >> 16) & 1u)) >> 16;     // RNE
    return (unsigned short)u;
}
static __device__ __forceinline__ float bf_lo(unsigned u) {
    return __uint_as_float(u << 16);
}
static __device__ __forceinline__ float bf_hi(unsigned u) {
    return __uint_as_float(u & 0xFFFF0000u);
}

// ---- CSR build (unchanged from R9) ----

__global__ __launch_bounds__(256) void k_bhist(const int* __restrict__ ei,
                                               int* __restrict__ bh) {
    __shared__ int cnts[NBUK];
    for (int b = threadIdx.x; b < NBUK; b += 256) cnts[b] = 0;
    __syncthreads();
    int base = blockIdx.x * CHUNK;
    for (int k = threadIdx.x; k < CHUNK; k += 256)
        atomicAdd(&cnts[ei[NE + base + k] >> 8], 1);
    __syncthreads();
    for (int b = threadIdx.x; b < NBUK; b += 256)
        bh[blockIdx.x * NBUK + b] = cnts[b];
}

__global__ __launch_bounds__(256) void k_scan1g(const int* __restrict__ bh,
                                                int* __restrict__ offs,
                                                int* __restrict__ bsum) {
    __shared__ int sm[256];
    int i = blockIdx.x * 256 + threadIdx.x;
    int buk = i >> 9, blk = i & (PBLK - 1);
    int x = bh[blk * NBUK + buk];
    sm[threadIdx.x] = x;
    __syncthreads();
    int v = x;
    for (int off = 1; off < 256; off <<= 1) {
        int t = (threadIdx.x >= (unsigned)off) ? sm[threadIdx.x - off] : 0;
        __syncthreads();
        v += t;
        sm[threadIdx.x] = v;
        __syncthreads();
    }
    offs[i] = v - x;
    if (threadIdx.x == 255) bsum[blockIdx.x] = v;
}

__global__ __launch_bounds__(1024) void k_scan2g(int* __restrict__ bsum, int nb) {
    __shared__ int sm[1024];
    int t = threadIdx.x;
    int x = (t < nb) ? bsum[t] : 0;
    sm[t] = x;
    __syncthreads();
    int v = x;
    for (int off = 1; off < 1024; off <<= 1) {
        int tt = (t >= off) ? sm[t - off] : 0;
        __syncthreads();
        v += tt;
        sm[t] = v;
        __syncthreads();
    }
    if (t < nb) bsum[t] = v - x;
}

__global__ __launch_bounds__(256) void k_part(const int* __restrict__ ei,
                                              const int* __restrict__ offs,
                                              const int* __restrict__ bsum,
                                              unsigned* __restrict__ part) {
    __shared__ int cur[NBUK];
    int blk = blockIdx.x;
    for (int b = threadIdx.x; b < NBUK; b += 256) {
        int i = b * PBLK + blk;
        cur[b] = offs[i] + bsum[i >> 8];
    }
    __syncthreads();
    int base = blk * CHUNK;
    for (int k = threadIdx.x; k < CHUNK; k += 256) {
        int s = ei[base + k];
        int d = ei[NE + base + k];
        int pos = atomicAdd(&cur[d >> 8], 1);
        part[pos] = (unsigned)s | ((unsigned)(d & 255) << 17);   // s < 2^17
    }
}

__global__ __launch_bounds__(256) void k_fineA(const unsigned* __restrict__ part,
                                               const int* __restrict__ offs,
                                               const int* __restrict__ bsum,
                                               int* __restrict__ rowp,
                                               float* __restrict__ dinv) {
    __shared__ int cnt[256];
    __shared__ int sm[256];
    int b = blockIdx.x;
    int row0 = b << 8;
    cnt[threadIdx.x] = 0;
    __syncthreads();
    int i0 = b * PBLK;
    int bstart = offs[i0] + bsum[i0 >> 8];
    int bend;
    if (b == NBUK - 1) bend = NE;
    else { int i1 = (b + 1) * PBLK; bend = offs[i1] + bsum[i1 >> 8]; }
    for (int k = bstart + threadIdx.x; k < bend; k += 256)
        atomicAdd(&cnt[part[k] >> 17], 1);
    __syncthreads();
    int x = cnt[threadIdx.x];
    sm[threadIdx.x] = x;
    __syncthreads();
    int v = x;
    for (int off = 1; off < 256; off <<= 1) {
        int t = (threadIdx.x >= (unsigned)off) ? sm[threadIdx.x - off] : 0;
        __syncthreads();
        v += t;
        sm[threadIdx.x] = v;
        __syncthreads();
    }
    int row = row0 + threadIdx.x;
    if (row < NN) {
        rowp[row] = bstart + v - x;
        dinv[row] = rsqrtf((float)x + 1.0f);     // +1 self-loop
    }
    if (row == NN - 1) rowp[NN] = NE;
}

__global__ __launch_bounds__(256) void k_fineB(const unsigned* __restrict__ part,
                                               const int* __restrict__ rowp,
                                               const int* __restrict__ offs,
                                               const int* __restrict__ bsum,
                                               const float* __restrict__ dinv,
                                               uint2* __restrict__ es2) {
    __shared__ int   cur[256];
    __shared__ float dlo[256];
    int b = blockIdx.x;
    int row0 = b << 8;
    int row = row0 + threadIdx.x;
    if (row < NN) {
        cur[threadIdx.x] = rowp[row];
        dlo[threadIdx.x] = dinv[row];
    } else {
        cur[threadIdx.x] = 0;
        dlo[threadIdx.x] = 0.0f;
    }
    __syncthreads();
    int i0 = b * PBLK;
    int bstart = offs[i0] + bsum[i0 >> 8];
    int bend;
    if (b == NBUK - 1) bend = NE;
    else { int i1 = (b + 1) * PBLK; bend = offs[i1] + bsum[i1 >> 8]; }
    for (int k = bstart + threadIdx.x; k < bend; k += 256) {
        unsigned p = part[k];
        int s  = (int)(p & 0x1FFFF);
        int dl = (int)(p >> 17);
        float c = dinv[s] * dlo[dl];
        int pos = atomicAdd(&cur[dl], 1);
        es2[pos] = make_uint2((unsigned)s, __float_as_uint(c));
    }
}

// ---- GEMM1: h16 = ori16 = bf16(in_feat[N,128] @ lin_w + lin_b), fp32 math.
// LDS: As[64][64] fp32 (16KB, XOR-swizzled 16B chunks) + Ws[128][64] (32KB,
// staged once) = 48KB -> 3 blocks/CU. global_load_lds staging; float4 reads.
__global__ __launch_bounds__(256) void k_gemmA(const float* __restrict__ A,
                                               const float* __restrict__ W,
                                               const float* __restrict__ bias,
                                               unsigned short* __restrict__ h16,
                                               unsigned short* __restrict__ ori16)
{
    __shared__ float As[64][64];
    __shared__ float Ws[128][64];
    const int tid = threadIdx.x;
    const int tx = tid & 15, ty = tid >> 4;
    const int c0 = tx * 4, r0 = ty * 4;
    const int row0 = blockIdx.x * 64;
    float acc[4][4] = {};

    // stage W[128][64] once (2048 x 16B chunks, linear)
    #pragma unroll
    for (int q = 0; q < 8; ++q) {
        int vid = q * 256 + tid;
        int wrow = vid >> 4, kq = vid & 15;
        GLD16(&W[(size_t)wrow * HF + kq * 4], (char*)Ws + (size_t)vid * 16);
    }
    // stage As for kt=0 (swizzled global source: phys chunk kqp holds logical kqp^sw(row))
    #pragma unroll
    for (int q = 0; q < 4; ++q) {
        int vid = q * 256 + tid;
        int row = vid >> 4, kqp = vid & 15;
        int kql = kqp ^ ((row >> 2) & 3);
        int grow = row0 + row; if (grow > NN - 1) grow = NN - 1;
        GLD16(&A[(size_t)grow * 128 + kql * 4], (char*)As + (size_t)vid * 16);
    }
    asm volatile("s_waitcnt vmcnt(0)" ::: "memory");
    __syncthreads();

    for (int kt = 0; kt < 2; ++kt) {
        const int sw = ty & 3;
        #pragma unroll 4
        for (int k4 = 0; k4 < 16; ++k4) {
            float a_[4][4];
            #pragma unroll
            for (int i = 0; i < 4; ++i) {
                int pk = k4 ^ sw;                 // (r0+i)>>2 == ty for i<4
                *reinterpret_cast<float4*>(a_[i]) =
                    *reinterpret_cast<const float4*>(&As[r0 + i][pk * 4]);
            }
            #pragma unroll
            for (int j = 0; j < 4; ++j) {
                float4 wv = *reinterpret_cast<const float4*>(
                    &Ws[kt * 64 + k4 * 4 + j][c0]);
                #pragma unroll
                for (int i = 0; i < 4; ++i) {
                    acc[i][0] += a_[i][j] * wv.x;
                    acc[i][1] += a_[i][j] * wv.y;
                    acc[i][2] += a_[i][j] * wv.z;
                    acc[i][3] += a_[i][j] * wv.w;
                }
            }
        }
        if (kt == 0) {
            __syncthreads();                      // compute done; As reusable
            #pragma unroll
            for (int q = 0; q < 4; ++q) {
                int vid = q * 256 + tid;
                int row = vid >> 4, kqp = vid & 15;
                int kql = kqp ^ ((row >> 2) & 3);
                int grow = row0 + row; if (grow > NN - 1) grow = NN - 1;
                GLD16(&A[(size_t)grow * 128 + 64 + kql * 4], (char*)As + (size_t)vid * 16);
            }
            asm volatile("s_waitcnt vmcnt(0)" ::: "memory");
            __syncthreads();
        }
    }

    float4 bv = *reinterpret_cast<const float4*>(&bias[c0]);
    #pragma unroll
    for (int i = 0; i < 4; ++i) {
        int r = row0 + r0 + i;
        if (r < NN) {
            ushort4 ob;
            ob.x = f2bf(acc[i][0] + bv.x); ob.y = f2bf(acc[i][1] + bv.y);
            ob.z = f2bf(acc[i][2] + bv.z); ob.w = f2bf(acc[i][3] + bv.w);
            *reinterpret_cast<ushort4*>(&h16[(size_t)r * HF + c0])   = ob;
            *reinterpret_cast<ushort4*>(&ori16[(size_t)r * HF + c0]) = ob;
        }
    }
}

// ---- GEMM2: hw16 = bf16(h16[N,64] @ conv_w), fp32 math, bf16 A in LDS
// (exact unpack). LDS: As16[64][32] uint (8KB, swizzled) + Ws[64][64] (16KB)
// = 24KB -> 6 blocks/CU. One barrier.
__global__ __launch_bounds__(256) void k_gemmB(const unsigned* __restrict__ h16u,
                                               const float* __restrict__ W,
                                               unsigned short* __restrict__ hw16)
{
    __shared__ unsigned As16[64][32];
    __shared__ float    Ws[64][64];
    const int tid = threadIdx.x;
    const int tx = tid & 15, ty = tid >> 4;
    const int c0 = tx * 4, r0 = ty * 4;
    const int row0 = blockIdx.x * 64;
    float acc[4][4] = {};

    // stage W[64][64] (1024 x 16B chunks)
    #pragma unroll
    for (int q = 0; q < 4; ++q) {
        int vid = q * 256 + tid;
        int wrow = vid >> 4, kq = vid & 15;
        GLD16(&W[(size_t)wrow * HF + kq * 4], (char*)Ws + (size_t)vid * 16);
    }
    // stage As16 (512 x 16B chunks; 8 chunks/row; swizzled: phys c8p holds logical c8p^sw)
    #pragma unroll
    for (int q = 0; q < 2; ++q) {
        int vid = q * 256 + tid;
        int row = vid >> 3, c8p = vid & 7;
        int c8l = c8p ^ ((row >> 2) & 3);
        int grow = row0 + row; if (grow > NN - 1) grow = NN - 1;
        GLD16(&h16u[(size_t)grow * 32 + c8l * 4], (char*)As16 + (size_t)vid * 16);
    }
    asm volatile("s_waitcnt vmcnt(0)" ::: "memory");
    __syncthreads();

    const int sw = ty & 3;
    #pragma unroll 2
    for (int k8 = 0; k8 < 8; ++k8) {
        unsigned u_[4][4];
        #pragma unroll
        for (int i = 0; i < 4; ++i) {
            int pc = k8 ^ sw;
            *reinterpret_cast<uint4*>(u_[i]) =
                *reinterpret_cast<const uint4*>(&As16[r0 + i][pc * 4]);
        }
        #pragma unroll
        for (int j = 0; j < 8; ++j) {
            float4 wv = *reinterpret_cast<const float4*>(&Ws[k8 * 8 + j][c0]);
            #pragma unroll
            for (int i = 0; i < 4; ++i) {
                unsigned comp = u_[i][j >> 1];
                float a = (j & 1) ? bf_hi(comp) : bf_lo(comp);
                acc[i][0] += a * wv.x;
                acc[i][1] += a * wv.y;
                acc[i][2] += a * wv.z;
                acc[i][3] += a * wv.w;
            }
        }
    }

    #pragma unroll
    for (int i = 0; i < 4; ++i) {
        int r = row0 + r0 + i;
        if (r < NN) {
            ushort4 ob;
            ob.x = f2bf(acc[i][0]); ob.y = f2bf(acc[i][1]);
            ob.z = f2bf(acc[i][2]); ob.w = f2bf(acc[i][3]);
            *reinterpret_cast<ushort4*>(&hw16[(size_t)r * HF + c0]) = ob;
        }
    }
}

// ---- Half-wave-per-row gather (unchanged from R9) ----
template<int FUSE_LN>
__global__ __launch_bounds__(256) void k_gather4(const int* __restrict__ rowp,
                                                 const uint2* __restrict__ es2,
                                                 const float* __restrict__ dinv,
                                                 const unsigned* __restrict__ hwu,
                                                 const float* __restrict__ cb,
                                                 const unsigned* __restrict__ ori16,
                                                 const float* __restrict__ lnw,
                                                 const float* __restrict__ lnb,
                                                 void* __restrict__ outv)
{
    int row = blockIdx.x * 8 + (threadIdx.x >> 5);
    if (row >= NN) return;                       // uniform per half-wave
    const int c2 = threadIdx.x & 31;
    const float dd = dinv[row];

    unsigned su = hwu[(size_t)row * 32 + c2];    // self-loop row
    float2 cbv = reinterpret_cast<const float2*>(cb)[c2];
    float s2 = dd * dd;
    float ax = fmaf(bf_lo(su), s2, cbv.x);
    float ay = fmaf(bf_hi(su), s2, cbv.y);

    const int start = rowp[row], end = rowp[row + 1];
    for (int base = start; base < end; base += 32) {
        int n = end - base;
        if (n > 32) n = 32;
        int   sl = 0;
        float cl = 0.0f;
        if (c2 < n) {
            uint2 p = es2[base + c2];
            sl = (int)p.x;
            cl = __uint_as_float(p.y);
        }
        int j = 0;
        for (; j + 8 <= n; j += 8) {
            unsigned uu[8]; float cc[8];
            #pragma unroll
            for (int q = 0; q < 8; ++q) {
                int s = __shfl(sl, j + q, 32);
                cc[q] = __shfl(cl, j + q, 32);
                uu[q] = hwu[(size_t)s * 32 + c2];
            }
            #pragma unroll
            for (int q = 0; q < 8; ++q) {
                ax += bf_lo(uu[q]) * cc[q];
                ay += bf_hi(uu[q]) * cc[q];
            }
        }
        for (; j < n; ++j) {
            int   s = __shfl(sl, j, 32);
            float c = __shfl(cl, j, 32);
            unsigned u = hwu[(size_t)s * 32 + c2];
            ax += bf_lo(u) * c;
            ay += bf_hi(u) * c;
        }
    }

    if (FUSE_LN) {
        unsigned uo = ori16[(size_t)row * 32 + c2];
        float v0 = ax + bf_lo(uo), v1 = ay + bf_hi(uo);
        float s = v0 + v1;
        #pragma unroll
        for (int off = 16; off > 0; off >>= 1) s += __shfl_xor(s, off, 32);
        float mu = s * (1.0f / 64.0f);
        float d0 = v0 - mu, d1 = v1 - mu;
        float q2 = d0 * d0 + d1 * d1;
        #pragma unroll
        for (int off = 16; off > 0; off >>= 1) q2 += __shfl_xor(q2, off, 32);
        float r = rsqrtf(q2 * (1.0f / 64.0f) + EPSV);
        float2 wv = reinterpret_cast<const float2*>(lnw)[c2];
        float2 bv = reinterpret_cast<const float2*>(lnb)[c2];
        float y0 = fmaxf(fmaf(d0 * r, wv.x, bv.x), 0.0f);
        float y1 = fmaxf(fmaf(d1 * r, wv.y, bv.y), 0.0f);
        ((unsigned*)outv)[(size_t)row * 32 + c2] =
            (unsigned)f2bf(y0) | ((unsigned)f2bf(y1) << 16);
    } else {
        reinterpret_cast<float2*>(outv)[(size_t)row * 32 + c2] = make_float2(ax, ay);
    }
}

extern "C" void kernel_launch(void* const* d_in, const int* in_sizes, int n_in,
                              void* d_out, int out_size, void* d_ws, size_t ws_size,
                              hipStream_t stream)
{
    const float* in_feat = (const float*)d_in[0];
    const int*   ei      = (const int*)d_in[1];   // [2][E]
    const float* lin_w   = (const float*)d_in[2];
    const float* lin_b   = (const float*)d_in[3];
    const float* conv_w  = (const float*)d_in[4];
    const float* conv_b  = (const float*)d_in[5];
    const float* ln_w    = (const float*)d_in[6]; // [3][64]
    const float* ln_b    = (const float*)d_in[7];
    float* out = (float*)d_out;
    float* ws  = (float*)d_ws;

    // Workspace (~62 MB):
    float*    dinv = ws;                         // NNP floats
    int*      rowp = (int*)(ws + NNP);           // NNP (rowp[NN] = NE)
    int*      bh   = rowp + NNP;                 // SCN
    int*      offs = bh + SCN;                   // SCN
    int*      bsum = offs + SCN;                 // 1024
    unsigned* part = (unsigned*)(bsum + 1024);   // NE uint (packed s|dstlow)
    uint2*    es2  = (uint2*)(part + NE);        // NE uint2 (exact CSR (src,coef))
    unsigned short* h16  = (unsigned short*)(es2 + NE);       // NN*HF bf16
    unsigned short* ori16 = h16 + (size_t)NN * HF;            // NN*HF bf16
    unsigned short* hw16  = ori16 + (size_t)NN * HF;          // NN*HF bf16
    unsigned* h16u  = (unsigned*)h16;
    unsigned* ori16u = (unsigned*)ori16;
    unsigned* hwu   = (unsigned*)hw16;

    // ---- CSR build (6 launches, zero global atomics) ----
    k_bhist<<<PBLK, 256, 0, stream>>>(ei, bh);
    k_scan1g<<<GB, 256, 0, stream>>>(bh, offs, bsum);
    k_scan2g<<<1, 1024, 0, stream>>>(bsum, GB);
    k_part<<<PBLK, 256, 0, stream>>>(ei, offs, bsum, part);
    k_fineA<<<NBUK, 256, 0, stream>>>(part, offs, bsum, rowp, dinv);
    k_fineB<<<NBUK, 256, 0, stream>>>(part, rowp, offs, bsum, dinv, es2);

    // ---- h16 = ori16 = bf16(in_feat @ lin_w + lin_b) ----
    k_gemmA<<<(NN + 63) / 64, 256, 0, stream>>>(in_feat, lin_w, lin_b, h16, ori16);

    // ---- 3 propagation steps ----
    for (int it = 0; it < 3; ++it) {
        k_gemmB<<<(NN + 63) / 64, 256, 0, stream>>>(h16u, conv_w, hw16);
        if (it < 2) {
            k_gather4<1><<<(NN + 7) / 8, 256, 0, stream>>>(
                rowp, es2, dinv, hwu, conv_b, ori16u,
                ln_w + (it + 1) * HF, ln_b + (it + 1) * HF, h16u);
        } else {
            k_gather4<0><<<(NN + 7) / 8, 256, 0, stream>>>(
                rowp, es2, dinv, hwu, conv_b, nullptr, nullptr, nullptr, out);
        }
    }
}

// Round 11
// 341.582 us; speedup vs baseline: 7.4525x; 1.0097x over previous
//
#include <hip/hip_runtime.h>

// GCN_56521769616159 R11: quarter-wave gather (16 lanes/row, uint2/lane) ->
// 32 outstanding row-loads/wave (R9 proved MLP is the gather lever: 2x MLP
// gave -33%; R10 gathers still latency-bound at 45% VALUBusy / 2.5TB/s).
// CSR-build kernels bumped to 512 threads (serial per-chunk loops halved).
// GEMMs unchanged from R10 (global_load_lds + swizzled-source staging).

static constexpr int NN    = 100000;
static constexpr int NE    = 1600000;
static constexpr int HF    = 64;
static constexpr int NNP   = 100352;        // NN padded to 256
static constexpr int NBUK  = 391;           // ceil(NN/256): bucket = dst>>8
static constexpr int PBLK  = 512;           // partition blocks
static constexpr int CHUNK = NE / PBLK;     // 3125 edges per partition block
static constexpr int SCN   = NBUK * PBLK;   // 200192 = 782*256
static constexpr int GB    = SCN / 256;     // 782 scan blocks
#define EPSV 1e-5f

#define GLD16(gp, lp) __builtin_amdgcn_global_load_lds( \
    (const __attribute__((address_space(1))) void*)(gp), \
    (__attribute__((address_space(3))) void*)(lp), 16, 0, 0)

static __device__ __forceinline__ unsigned short f2bf(float f) {
    unsigned u = __float_as_uint(f);
    u = (u + 0x7FFFu + ((u >> 16) & 1u)) >> 16;     // RNE
    return (unsigned short)u;
}
static __device__ __forceinline__ float bf_lo(unsigned u) {
    return __uint_as_float(u << 16);
}
static __device__ __forceinline__ float bf_hi(unsigned u) {
    return __uint_as_float(u & 0xFFFF0000u);
}

// ---- CSR build (512-thread variants) ----

__global__ __launch_bounds__(512) void k_bhist(const int* __restrict__ ei,
                                               int* __restrict__ bh) {
    __shared__ int cnts[NBUK];
    for (int b = threadIdx.x; b < NBUK; b += 512) cnts[b] = 0;
    __syncthreads();
    int base = blockIdx.x * CHUNK;
    for (int k = threadIdx.x; k < CHUNK; k += 512)
        atomicAdd(&cnts[ei[NE + base + k] >> 8], 1);
    __syncthreads();
    for (int b = threadIdx.x; b < NBUK; b += 512)
        bh[blockIdx.x * NBUK + b] = cnts[b];
}

__global__ __launch_bounds__(256) void k_scan1g(const int* __restrict__ bh,
                                                int* __restrict__ offs,
                                                int* __restrict__ bsum) {
    __shared__ int sm[256];
    int i = blockIdx.x * 256 + threadIdx.x;
    int buk = i >> 9, blk = i & (PBLK - 1);
    int x = bh[blk * NBUK + buk];
    sm[threadIdx.x] = x;
    __syncthreads();
    int v = x;
    for (int off = 1; off < 256; off <<= 1) {
        int t = (threadIdx.x >= (unsigned)off) ? sm[threadIdx.x - off] : 0;
        __syncthreads();
        v += t;
        sm[threadIdx.x] = v;
        __syncthreads();
    }
    offs[i] = v - x;
    if (threadIdx.x == 255) bsum[blockIdx.x] = v;
}

__global__ __launch_bounds__(1024) void k_scan2g(int* __restrict__ bsum, int nb) {
    __shared__ int sm[1024];
    int t = threadIdx.x;
    int x = (t < nb) ? bsum[t] : 0;
    sm[t] = x;
    __syncthreads();
    int v = x;
    for (int off = 1; off < 1024; off <<= 1) {
        int tt = (t >= off) ? sm[t - off] : 0;
        __syncthreads();
        v += tt;
        sm[t] = v;
        __syncthreads();
    }
    if (t < nb) bsum[t] = v - x;
}

__global__ __launch_bounds__(512) void k_part(const int* __restrict__ ei,
                                              const int* __restrict__ offs,
                                              const int* __restrict__ bsum,
                                              unsigned* __restrict__ part) {
    __shared__ int cur[NBUK];
    int blk = blockIdx.x;
    for (int b = threadIdx.x; b < NBUK; b += 512) {
        int i = b * PBLK + blk;
        cur[b] = offs[i] + bsum[i >> 8];
    }
    __syncthreads();
    int base = blk * CHUNK;
    for (int k = threadIdx.x; k < CHUNK; k += 512) {
        int s = ei[base + k];
        int d = ei[NE + base + k];
        int pos = atomicAdd(&cur[d >> 8], 1);
        part[pos] = (unsigned)s | ((unsigned)(d & 255) << 17);   // s < 2^17
    }
}

__global__ __launch_bounds__(512) void k_fineA(const unsigned* __restrict__ part,
                                               const int* __restrict__ offs,
                                               const int* __restrict__ bsum,
                                               int* __restrict__ rowp,
                                               float* __restrict__ dinv) {
    __shared__ int cnt[256];
    __shared__ int sm[256];
    int b = blockIdx.x;
    int row0 = b << 8;
    if (threadIdx.x < 256) cnt[threadIdx.x] = 0;
    __syncthreads();
    int i0 = b * PBLK;
    int bstart = offs[i0] + bsum[i0 >> 8];
    int bend;
    if (b == NBUK - 1) bend = NE;
    else { int i1 = (b + 1) * PBLK; bend = offs[i1] + bsum[i1 >> 8]; }
    for (int k = bstart + threadIdx.x; k < bend; k += 512)
        atomicAdd(&cnt[part[k] >> 17], 1);
    __syncthreads();
    int x = 0, v = 0;
    if (threadIdx.x < 256) { x = cnt[threadIdx.x]; sm[threadIdx.x] = x; }
    __syncthreads();
    v = x;
    for (int off = 1; off < 256; off <<= 1) {
        int t = 0;
        if (threadIdx.x < 256 && threadIdx.x >= (unsigned)off) t = sm[threadIdx.x - off];
        __syncthreads();
        if (threadIdx.x < 256) { v += t; sm[threadIdx.x] = v; }
        __syncthreads();
    }
    if (threadIdx.x < 256) {
        int row = row0 + threadIdx.x;
        if (row < NN) {
            rowp[row] = bstart + v - x;
            dinv[row] = rsqrtf((float)x + 1.0f);     // +1 self-loop
        }
        if (row == NN - 1) rowp[NN] = NE;
    }
}

__global__ __launch_bounds__(512) void k_fineB(const unsigned* __restrict__ part,
                                               const int* __restrict__ rowp,
                                               const int* __restrict__ offs,
                                               const int* __restrict__ bsum,
                                               const float* __restrict__ dinv,
                                               uint2* __restrict__ es2) {
    __shared__ int   cur[256];
    __shared__ float dlo[256];
    int b = blockIdx.x;
    int row0 = b << 8;
    if (threadIdx.x < 256) {
        int row = row0 + threadIdx.x;
        if (row < NN) {
            cur[threadIdx.x] = rowp[row];
            dlo[threadIdx.x] = dinv[row];
        } else {
            cur[threadIdx.x] = 0;
            dlo[threadIdx.x] = 0.0f;
        }
    }
    __syncthreads();
    int i0 = b * PBLK;
    int bstart = offs[i0] + bsum[i0 >> 8];
    int bend;
    if (b == NBUK - 1) bend = NE;
    else { int i1 = (b + 1) * PBLK; bend = offs[i1] + bsum[i1 >> 8]; }
    for (int k = bstart + threadIdx.x; k < bend; k += 512) {
        unsigned p = part[k];
        int s  = (int)(p & 0x1FFFF);
        int dl = (int)(p >> 17);
        float c = dinv[s] * dlo[dl];
        int pos = atomicAdd(&cur[dl], 1);
        es2[pos] = make_uint2((unsigned)s, __float_as_uint(c));
    }
}

// ---- GEMM1 (unchanged from R10): h16 = ori16 = bf16(in_feat @ lin_w + b) ----
__global__ __launch_bounds__(256) void k_gemmA(const float* __restrict__ A,
                                               const float* __restrict__ W,
                                               const float* __restrict__ bias,
                                               unsigned short* __restrict__ h16,
                                               unsigned short* __restrict__ ori16)
{
    __shared__ float As[64][64];
    __shared__ float Ws[128][64];
    const int tid = threadIdx.x;
    const int tx = tid & 15, ty = tid >> 4;
    const int c0 = tx * 4, r0 = ty * 4;
    const int row0 = blockIdx.x * 64;
    float acc[4][4] = {};

    #pragma unroll
    for (int q = 0; q < 8; ++q) {
        int vid = q * 256 + tid;
        int wrow = vid >> 4, kq = vid & 15;
        GLD16(&W[(size_t)wrow * HF + kq * 4], (char*)Ws + (size_t)vid * 16);
    }
    #pragma unroll
    for (int q = 0; q < 4; ++q) {
        int vid = q * 256 + tid;
        int row = vid >> 4, kqp = vid & 15;
        int kql = kqp ^ ((row >> 2) & 3);
        int grow = row0 + row; if (grow > NN - 1) grow = NN - 1;
        GLD16(&A[(size_t)grow * 128 + kql * 4], (char*)As + (size_t)vid * 16);
    }
    asm volatile("s_waitcnt vmcnt(0)" ::: "memory");
    __syncthreads();

    for (int kt = 0; kt < 2; ++kt) {
        const int sw = ty & 3;
        #pragma unroll 4
        for (int k4 = 0; k4 < 16; ++k4) {
            float a_[4][4];
            #pragma unroll
            for (int i = 0; i < 4; ++i) {
                int pk = k4 ^ sw;
                *reinterpret_cast<float4*>(a_[i]) =
                    *reinterpret_cast<const float4*>(&As[r0 + i][pk * 4]);
            }
            #pragma unroll
            for (int j = 0; j < 4; ++j) {
                float4 wv = *reinterpret_cast<const float4*>(
                    &Ws[kt * 64 + k4 * 4 + j][c0]);
                #pragma unroll
                for (int i = 0; i < 4; ++i) {
                    acc[i][0] += a_[i][j] * wv.x;
                    acc[i][1] += a_[i][j] * wv.y;
                    acc[i][2] += a_[i][j] * wv.z;
                    acc[i][3] += a_[i][j] * wv.w;
                }
            }
        }
        if (kt == 0) {
            __syncthreads();
            #pragma unroll
            for (int q = 0; q < 4; ++q) {
                int vid = q * 256 + tid;
                int row = vid >> 4, kqp = vid & 15;
                int kql = kqp ^ ((row >> 2) & 3);
                int grow = row0 + row; if (grow > NN - 1) grow = NN - 1;
                GLD16(&A[(size_t)grow * 128 + 64 + kql * 4], (char*)As + (size_t)vid * 16);
            }
            asm volatile("s_waitcnt vmcnt(0)" ::: "memory");
            __syncthreads();
        }
    }

    float4 bv = *reinterpret_cast<const float4*>(&bias[c0]);
    #pragma unroll
    for (int i = 0; i < 4; ++i) {
        int r = row0 + r0 + i;
        if (r < NN) {
            ushort4 ob;
            ob.x = f2bf(acc[i][0] + bv.x); ob.y = f2bf(acc[i][1] + bv.y);
            ob.z = f2bf(acc[i][2] + bv.z); ob.w = f2bf(acc[i][3] + bv.w);
            *reinterpret_cast<ushort4*>(&h16[(size_t)r * HF + c0])   = ob;
            *reinterpret_cast<ushort4*>(&ori16[(size_t)r * HF + c0]) = ob;
        }
    }
}

// ---- GEMM2 (unchanged from R10): hw16 = bf16(h16 @ conv_w) ----
__global__ __launch_bounds__(256) void k_gemmB(const unsigned* __restrict__ h16u,
                                               const float* __restrict__ W,
                                               unsigned short* __restrict__ hw16)
{
    __shared__ unsigned As16[64][32];
    __shared__ float    Ws[64][64];
    const int tid = threadIdx.x;
    const int tx = tid & 15, ty = tid >> 4;
    const int c0 = tx * 4, r0 = ty * 4;
    const int row0 = blockIdx.x * 64;
    float acc[4][4] = {};

    #pragma unroll
    for (int q = 0; q < 4; ++q) {
        int vid = q * 256 + tid;
        int wrow = vid >> 4, kq = vid & 15;
        GLD16(&W[(size_t)wrow * HF + kq * 4], (char*)Ws + (size_t)vid * 16);
    }
    #pragma unroll
    for (int q = 0; q < 2; ++q) {
        int vid = q * 256 + tid;
        int row = vid >> 3, c8p = vid & 7;
        int c8l = c8p ^ ((row >> 2) & 3);
        int grow = row0 + row; if (grow > NN - 1) grow = NN - 1;
        GLD16(&h16u[(size_t)grow * 32 + c8l * 4], (char*)As16 + (size_t)vid * 16);
    }
    asm volatile("s_waitcnt vmcnt(0)" ::: "memory");
    __syncthreads();

    const int sw = ty & 3;
    #pragma unroll 2
    for (int k8 = 0; k8 < 8; ++k8) {
        unsigned u_[4][4];
        #pragma unroll
        for (int i = 0; i < 4; ++i) {
            int pc = k8 ^ sw;
            *reinterpret_cast<uint4*>(u_[i]) =
                *reinterpret_cast<const uint4*>(&As16[r0 + i][pc * 4]);
        }
        #pragma unroll
        for (int j = 0; j < 8; ++j) {
            float4 wv = *reinterpret_cast<const float4*>(&Ws[k8 * 8 + j][c0]);
            #pragma unroll
            for (int i = 0; i < 4; ++i) {
                unsigned comp = u_[i][j >> 1];
                float a = (j & 1) ? bf_hi(comp) : bf_lo(comp);
                acc[i][0] += a * wv.x;
                acc[i][1] += a * wv.y;
                acc[i][2] += a * wv.z;
                acc[i][3] += a * wv.w;
            }
        }
    }

    #pragma unroll
    for (int i = 0; i < 4; ++i) {
        int r = row0 + r0 + i;
        if (r < NN) {
            ushort4 ob;
            ob.x = f2bf(acc[i][0]); ob.y = f2bf(acc[i][1]);
            ob.z = f2bf(acc[i][2]); ob.w = f2bf(acc[i][3]);
            *reinterpret_cast<ushort4*>(&hw16[(size_t)r * HF + c0]) = ob;
        }
    }
}

// ---- Quarter-wave gather: 16 lanes per row, uint2 (4 bf16) per lane.
// 4 rows/wave, 8-deep unroll -> 32 outstanding row-loads per wave.
// Edge accumulation order per column identical to R9/R10 (absmax-stable).
template<int FUSE_LN>
__global__ __launch_bounds__(256) void k_gather5(const int* __restrict__ rowp,
                                                 const uint2* __restrict__ es2,
                                                 const float* __restrict__ dinv,
                                                 const uint2* __restrict__ hwu2,
                                                 const float* __restrict__ cb,
                                                 const uint2* __restrict__ ori2,
                                                 const float* __restrict__ lnw,
                                                 const float* __restrict__ lnb,
                                                 void* __restrict__ outv)
{
    int row = blockIdx.x * 16 + (threadIdx.x >> 4);
    if (row >= NN) return;                       // uniform per 16-lane group
    const int c4 = threadIdx.x & 15;             // column quad (4 bf16 = uint2)
    const float dd = dinv[row];

    uint2 su = hwu2[(size_t)row * 16 + c4];      // self-loop row
    float4 cbv = reinterpret_cast<const float4*>(cb)[c4];
    float s2 = dd * dd;
    float a0 = fmaf(bf_lo(su.x), s2, cbv.x);
    float a1 = fmaf(bf_hi(su.x), s2, cbv.y);
    float a2 = fmaf(bf_lo(su.y), s2, cbv.z);
    float a3 = fmaf(bf_hi(su.y), s2, cbv.w);

    const int start = rowp[row], end = rowp[row + 1];
    for (int base = start; base < end; base += 16) {
        int n = end - base;
        if (n > 16) n = 16;
        int   sl = 0;
        float cl = 0.0f;
        if (c4 < n) {
            uint2 p = es2[base + c4];
            sl = (int)p.x;
            cl = __uint_as_float(p.y);
        }
        int j = 0;
        for (; j + 8 <= n; j += 8) {
            uint2 uu[8]; float cc[8];
            #pragma unroll
            for (int q = 0; q < 8; ++q) {
                int s = __shfl(sl, j + q, 16);
                cc[q] = __shfl(cl, j + q, 16);
                uu[q] = hwu2[(size_t)s * 16 + c4];
            }
            #pragma unroll
            for (int q = 0; q < 8; ++q) {
                a0 += bf_lo(uu[q].x) * cc[q];
                a1 += bf_hi(uu[q].x) * cc[q];
                a2 += bf_lo(uu[q].y) * cc[q];
                a3 += bf_hi(uu[q].y) * cc[q];
            }
        }
        for (; j < n; ++j) {
            int   s = __shfl(sl, j, 16);
            float c = __shfl(cl, j, 16);
            uint2 u = hwu2[(size_t)s * 16 + c4];
            a0 += bf_lo(u.x) * c;
            a1 += bf_hi(u.x) * c;
            a2 += bf_lo(u.y) * c;
            a3 += bf_hi(u.y) * c;
        }
    }

    if (FUSE_LN) {
        uint2 uo = ori2[(size_t)row * 16 + c4];
        float v0 = a0 + bf_lo(uo.x), v1 = a1 + bf_hi(uo.x);
        float v2 = a2 + bf_lo(uo.y), v3 = a3 + bf_hi(uo.y);
        float s = (v0 + v1) + (v2 + v3);
        #pragma unroll
        for (int off = 8; off > 0; off >>= 1) s += __shfl_xor(s, off, 16);
        float mu = s * (1.0f / 64.0f);
        float d0 = v0 - mu, d1 = v1 - mu, d2 = v2 - mu, d3 = v3 - mu;
        float q2 = (d0 * d0 + d1 * d1) + (d2 * d2 + d3 * d3);
        #pragma unroll
        for (int off = 8; off > 0; off >>= 1) q2 += __shfl_xor(q2, off, 16);
        float r = rsqrtf(q2 * (1.0f / 64.0f) + EPSV);
        float4 wv = reinterpret_cast<const float4*>(lnw)[c4];
        float4 bv = reinterpret_cast<const float4*>(lnb)[c4];
        float y0 = fmaxf(fmaf(d0 * r, wv.x, bv.x), 0.0f);
        float y1 = fmaxf(fmaf(d1 * r, wv.y, bv.y), 0.0f);
        float y2 = fmaxf(fmaf(d2 * r, wv.z, bv.z), 0.0f);
        float y3 = fmaxf(fmaf(d3 * r, wv.w, bv.w), 0.0f);
        reinterpret_cast<uint2*>(outv)[(size_t)row * 16 + c4] = make_uint2(
            (unsigned)f2bf(y0) | ((unsigned)f2bf(y1) << 16),
            (unsigned)f2bf(y2) | ((unsigned)f2bf(y3) << 16));
    } else {
        reinterpret_cast<float4*>(outv)[(size_t)row * 16 + c4] =
            make_float4(a0, a1, a2, a3);
    }
}

extern "C" void kernel_launch(void* const* d_in, const int* in_sizes, int n_in,
                              void* d_out, int out_size, void* d_ws, size_t ws_size,
                              hipStream_t stream)
{
    const float* in_feat = (const float*)d_in[0];
    const int*   ei      = (const int*)d_in[1];   // [2][E]
    const float* lin_w   = (const float*)d_in[2];
    const float* lin_b   = (const float*)d_in[3];
    const float* conv_w  = (const float*)d_in[4];
    const float* conv_b  = (const float*)d_in[5];
    const float* ln_w    = (const float*)d_in[6]; // [3][64]
    const float* ln_b    = (const float*)d_in[7];
    float* out = (float*)d_out;
    float* ws  = (float*)d_ws;

    // Workspace (~62 MB):
    float*    dinv = ws;                         // NNP floats
    int*      rowp = (int*)(ws + NNP);           // NNP (rowp[NN] = NE)
    int*      bh   = rowp + NNP;                 // SCN
    int*      offs = bh + SCN;                   // SCN
    int*      bsum = offs + SCN;                 // 1024
    unsigned* part = (unsigned*)(bsum + 1024);   // NE uint (packed s|dstlow)
    uint2*    es2  = (uint2*)(part + NE);        // NE uint2 (exact CSR (src,coef))
    unsigned short* h16  = (unsigned short*)(es2 + NE);       // NN*HF bf16
    unsigned short* ori16 = h16 + (size_t)NN * HF;            // NN*HF bf16
    unsigned short* hw16  = ori16 + (size_t)NN * HF;          // NN*HF bf16
    unsigned* h16u  = (unsigned*)h16;
    uint2*    ori2  = (uint2*)ori16;
    uint2*    hwu2  = (uint2*)hw16;

    // ---- CSR build (6 launches, zero global atomics) ----
    k_bhist<<<PBLK, 512, 0, stream>>>(ei, bh);
    k_scan1g<<<GB, 256, 0, stream>>>(bh, offs, bsum);
    k_scan2g<<<1, 1024, 0, stream>>>(bsum, GB);
    k_part<<<PBLK, 512, 0, stream>>>(ei, offs, bsum, part);
    k_fineA<<<NBUK, 512, 0, stream>>>(part, offs, bsum, rowp, dinv);
    k_fineB<<<NBUK, 512, 0, stream>>>(part, rowp, offs, bsum, dinv, es2);

    // ---- h16 = ori16 = bf16(in_feat @ lin_w + lin_b) ----
    k_gemmA<<<(NN + 63) / 64, 256, 0, stream>>>(in_feat, lin_w, lin_b, h16, ori16);

    // ---- 3 propagation steps ----
    for (int it = 0; it < 3; ++it) {
        k_gemmB<<<(NN + 63) / 64, 256, 0, stream>>>(h16u, conv_w, hw16);
        if (it < 2) {
            k_gather5<1><<<(NN + 15) / 16, 256, 0, stream>>>(
                rowp, es2, dinv, hwu2, conv_b, ori2,
                ln_w + (it + 1) * HF, ln_b + (it + 1) * HF, h16u);
        } else {
            k_gather5<0><<<(NN + 15) / 16, 256, 0, stream>>>(
                rowp, es2, dinv, hwu2, conv_b, nullptr, nullptr, nullptr, out);
        }
    }
}